// Round 2
// baseline (209.316 us; speedup 1.0000x reference)
//
#include <hip/hip_runtime.h>

#define BINS 5
#define PTS  2
constexpr int Bx = 2, Cc = 256, Hh = 100, Ww = 152;
constexpr int HW = Hh * Ww;          // 15200
constexpr int NTILE = 238;           // merge pixel tiles (64 px each)
constexpr float EPS_DIV = 1e-6f;
constexpr float GN_EPS  = 1e-5f;

typedef __attribute__((ext_vector_type(8))) _Float16 hfrag;  // 8 fp16 (4 VGPRs)
typedef __attribute__((ext_vector_type(2))) _Float16 h2;     // packed pair
typedef __attribute__((ext_vector_type(4))) float f32x4;     // MFMA C/D

__device__ __forceinline__ ushort f2h(float f) {
    return __builtin_bit_cast(ushort, (_Float16)f);
}
__device__ __forceinline__ float hlo(unsigned u) {
    return (float)__builtin_bit_cast(_Float16, (ushort)(u & 0xffffu));
}
__device__ __forceinline__ float hhi(unsigned u) {
    return (float)__builtin_bit_cast(_Float16, (ushort)(u >> 16));
}

#define GLL16(g, l) __builtin_amdgcn_global_load_lds( \
    (const __attribute__((address_space(1))) unsigned*)(g), \
    (__attribute__((address_space(3))) unsigned*)(l), 16, 0, 0)

// ---------------------------------------------------------------------------
// K0: convert ef_w, hm1_w, merge_w to fp16 (each 131072 elems)
// ---------------------------------------------------------------------------
__global__ __launch_bounds__(256)
void k_wconv(const float* __restrict__ efw, const float* __restrict__ w1,
             const float* __restrict__ mw, ushort* __restrict__ wb)
{
    int gid = blockIdx.x * 256 + threadIdx.x;
    int e = gid * 4;
    int arr = e >> 17, off = e & 131071;
    const float* src = arr == 0 ? efw : (arr == 1 ? w1 : mw);
    float4 v = *(const float4*)(src + off);
    ushort4 o = { f2h(v.x), f2h(v.y), f2h(v.z), f2h(v.w) };
    *(ushort4*)(wb + e) = o;
}

// ---------------------------------------------------------------------------
// K0b: transpose+convert x[b][c][hw] fp32 -> xbt[b][hw][c] fp16
// ---------------------------------------------------------------------------
__global__ __launch_bounds__(256)
void k_xt(const float* __restrict__ x, ushort* __restrict__ xbt)
{
    __shared__ float tile[32][33];
    const int t = threadIdx.x;
    const int hw0 = blockIdx.x * 32;
    const int c0 = blockIdx.y * 32;
    const int b = blockIdx.z;
    const float* xb = x + ((size_t)b * Cc + c0) * HW + hw0;
    const int tx = t & 31, ty = t >> 5;
    #pragma unroll
    for (int r = 0; r < 4; r++) {
        int c = ty + r * 8;
        tile[c][tx] = xb[(size_t)c * HW + tx];
    }
    __syncthreads();
    const int hwl = t >> 3, c4 = (t & 7) * 4;
    ushort4 o = { f2h(tile[c4 + 0][hwl]), f2h(tile[c4 + 1][hwl]),
                  f2h(tile[c4 + 2][hwl]), f2h(tile[c4 + 3][hwl]) };
    *(ushort4*)&xbt[((size_t)b * HW + hw0 + hwl) * Cc + c0 + c4] = o;
}

// ---------------------------------------------------------------------------
// K1: efp[b][p][pix][c] (fp16) = ef_w @ x + ef_b.  A-resident persistent
// blocks: A chunk (128 rows x 256, XOR-swizzled) staged once via
// global_load_lds; B tiles (64 px) double-buffered with counted vmcnt(4);
// raw s_barrier (loads stay in flight).  8 waves = 4 M-waves x 2 px-groups.
// ---------------------------------------------------------------------------
__global__ __launch_bounds__(512)
void k_ef(const ushort* __restrict__ xbt, const ushort* __restrict__ wbe,
          const float* __restrict__ efb, ushort* __restrict__ efp)
{
    __shared__ ushort Alds[128 * 256];   // 64 KB
    __shared__ ushort Bl0[64 * 256];     // 32 KB
    __shared__ ushort Bl1[64 * 256];     // 32 KB
    const int t  = threadIdx.x;
    const int wv = t >> 6, ln = t & 63;
    const int quad = ln >> 4, l16 = ln & 15;
    const int mwv = wv & 3, ngr = wv >> 2;
    const int xr = l16 & 7;
    const int bx = blockIdx.x;            // 0..29
    const int n0 = blockIdx.y;            // 0..3 (128-row chunk of 512)
    const int b  = blockIdx.z;
    const ushort* xb = xbt + (size_t)b * HW * Cc;
    const ushort* wA = wbe + (size_t)n0 * 128 * 256;
    const int ntl = (237 - bx) / 30 + 1;  // >= 2 always

    // stage A once (inverse-swizzled source -> linear LDS; read with XOR)
    #pragma unroll
    for (int j = 0; j < 8; j++) {
        int unit = j * 512 + t;
        int row = unit >> 5, c8 = unit & 31;
        const ushort* g = wA + row * 256 + ((c8 ^ (row & 7)) << 3);
        ushort* l = Alds + (j * 512 + wv * 64) * 8;
        GLL16(g, l);
    }
    auto stageB = [&](int tt, ushort* dst) {
        int tp0 = tt * 64;
        #pragma unroll
        for (int j = 0; j < 4; j++) {
            int unit = j * 512 + t;
            int prow = unit >> 5, c8 = unit & 31;
            int pq = tp0 + prow; if (pq > HW - 1) pq = HW - 1;
            const ushort* g = xb + (size_t)pq * 256 + ((c8 ^ (prow & 7)) << 3);
            ushort* l = dst + (j * 512 + wv * 64) * 8;
            GLL16(g, l);
        }
    };
    stageB(bx, Bl0);
    stageB(bx + 30, Bl1);
    asm volatile("s_waitcnt vmcnt(4)" ::: "memory");   // A + B0 complete
    __builtin_amdgcn_s_barrier();
    __builtin_amdgcn_sched_barrier(0);

    float bias[2][4];
    #pragma unroll
    for (int dt = 0; dt < 2; dt++)
        #pragma unroll
        for (int r = 0; r < 4; r++)
            bias[dt][r] = efb[n0 * 128 + mwv * 32 + dt * 16 + quad * 4 + r];

    const int aof0 = (mwv * 32 + l16) * 256;
    const int aof1 = (mwv * 32 + 16 + l16) * 256;
    const int bof0 = (ngr * 32 + l16) * 256;
    const int bof1 = (ngr * 32 + 16 + l16) * 256;
    const int p_ = n0 >> 1;
    const int cb = (n0 & 1) * 128 + mwv * 32;
    ushort* outb = efp + (size_t)((b * PTS + p_) * HW) * Cc;

    for (int it = 0; it < ntl; it++) {
        const int tp0 = (bx + it * 30) * 64;
        const ushort* bb = (it & 1) ? Bl1 : Bl0;
        f32x4 acc[2][2];
        #pragma unroll
        for (int i = 0; i < 2; i++)
            #pragma unroll
            for (int j = 0; j < 2; j++) acc[i][j] = (f32x4){0.f, 0.f, 0.f, 0.f};
        #pragma unroll
        for (int s = 0; s < 8; s++) {
            const int co = (((s * 4 + quad) ^ xr) << 3);
            hfrag a0 = *(const hfrag*)&Alds[aof0 + co];
            hfrag a1 = *(const hfrag*)&Alds[aof1 + co];
            hfrag b0 = *(const hfrag*)&bb[bof0 + co];
            hfrag b1 = *(const hfrag*)&bb[bof1 + co];
            acc[0][0] = __builtin_amdgcn_mfma_f32_16x16x32_f16(a0, b0, acc[0][0], 0, 0, 0);
            acc[0][1] = __builtin_amdgcn_mfma_f32_16x16x32_f16(a0, b1, acc[0][1], 0, 0, 0);
            acc[1][0] = __builtin_amdgcn_mfma_f32_16x16x32_f16(a1, b0, acc[1][0], 0, 0, 0);
            acc[1][1] = __builtin_amdgcn_mfma_f32_16x16x32_f16(a1, b1, acc[1][1], 0, 0, 0);
        }
        #pragma unroll
        for (int dt = 0; dt < 2; dt++)
            #pragma unroll
            for (int pt = 0; pt < 2; pt++) {
                int pix = tp0 + ngr * 32 + pt * 16 + l16;
                if (pix < HW) {
                    ushort4 o = { f2h(acc[dt][pt][0] + bias[dt][0]),
                                  f2h(acc[dt][pt][1] + bias[dt][1]),
                                  f2h(acc[dt][pt][2] + bias[dt][2]),
                                  f2h(acc[dt][pt][3] + bias[dt][3]) };
                    *(ushort4*)&outb[(size_t)pix * Cc + cb + dt * 16 + quad * 4] = o;
                }
            }
        if (it + 1 < ntl) {
            __builtin_amdgcn_s_barrier();              // reads of bb done
            if (it + 2 < ntl) {
                stageB(bx + (it + 2) * 30, (it & 1) ? Bl1 : Bl0);
                asm volatile("s_waitcnt vmcnt(4)" ::: "memory");
            } else {
                asm volatile("s_waitcnt vmcnt(0)" ::: "memory");
            }
            __builtin_amdgcn_s_barrier();              // next buffer ready
            __builtin_amdgcn_sched_barrier(0);
        }
    }
}

// ---------------------------------------------------------------------------
// K2: partial heat logits.  Same A-resident template; A = 128-row chunk of
// w1[p]; epilogue reduces w2*relu(.) over this chunk's rows and writes
// hp[n0][b][p][pix].  k_hexp finishes exp(h0+h1+b2).
// ---------------------------------------------------------------------------
__global__ __launch_bounds__(512)
void k_heat(const ushort* __restrict__ efp, const ushort* __restrict__ wb1,
            const float* __restrict__ b1, const float* __restrict__ w2,
            float* __restrict__ hp)
{
    __shared__ ushort Alds[128 * 256];
    __shared__ ushort Bl0[64 * 256];
    __shared__ ushort Bl1[64 * 256];
    __shared__ float red[2][4][32];
    const int t  = threadIdx.x;
    const int wv = t >> 6, ln = t & 63;
    const int quad = ln >> 4, l16 = ln & 15;
    const int mwv = wv & 3, ngr = wv >> 2;
    const int xr = l16 & 7;
    const int bx = blockIdx.x;            // 0..29
    const int p  = blockIdx.y >> 1;
    const int n0 = blockIdx.y & 1;        // 128-row chunk of 256 hidden
    const int b  = blockIdx.z;
    const ushort* eb = efp + (size_t)((b * PTS + p) * HW) * Cc;
    const ushort* wA = wb1 + (size_t)p * Cc * Cc + (size_t)n0 * 128 * 256;
    const int ntl = (237 - bx) / 30 + 1;

    #pragma unroll
    for (int j = 0; j < 8; j++) {
        int unit = j * 512 + t;
        int row = unit >> 5, c8 = unit & 31;
        const ushort* g = wA + row * 256 + ((c8 ^ (row & 7)) << 3);
        ushort* l = Alds + (j * 512 + wv * 64) * 8;
        GLL16(g, l);
    }
    auto stageB = [&](int tt, ushort* dst) {
        int tp0 = tt * 64;
        #pragma unroll
        for (int j = 0; j < 4; j++) {
            int unit = j * 512 + t;
            int prow = unit >> 5, c8 = unit & 31;
            int pq = tp0 + prow; if (pq > HW - 1) pq = HW - 1;
            const ushort* g = eb + (size_t)pq * 256 + ((c8 ^ (prow & 7)) << 3);
            ushort* l = dst + (j * 512 + wv * 64) * 8;
            GLL16(g, l);
        }
    };
    stageB(bx, Bl0);
    stageB(bx + 30, Bl1);
    asm volatile("s_waitcnt vmcnt(4)" ::: "memory");
    __builtin_amdgcn_s_barrier();
    __builtin_amdgcn_sched_barrier(0);

    const float* b1p = b1 + p * 256;
    const float* w2p = w2 + p * 256;
    float b1v[2][4], w2v[2][4];
    #pragma unroll
    for (int dt = 0; dt < 2; dt++)
        #pragma unroll
        for (int r = 0; r < 4; r++) {
            int gch = n0 * 128 + mwv * 32 + dt * 16 + quad * 4 + r;
            b1v[dt][r] = b1p[gch];
            w2v[dt][r] = w2p[gch];
        }

    const int aof0 = (mwv * 32 + l16) * 256;
    const int aof1 = (mwv * 32 + 16 + l16) * 256;
    const int bof0 = (ngr * 32 + l16) * 256;
    const int bof1 = (ngr * 32 + 16 + l16) * 256;
    float* hpo = hp + (size_t)n0 * (Bx * PTS * HW) + (size_t)(b * PTS + p) * HW;

    for (int it = 0; it < ntl; it++) {
        const int tp0 = (bx + it * 30) * 64;
        const ushort* bb = (it & 1) ? Bl1 : Bl0;
        f32x4 acc[2][2];
        #pragma unroll
        for (int i = 0; i < 2; i++)
            #pragma unroll
            for (int j = 0; j < 2; j++) acc[i][j] = (f32x4){0.f, 0.f, 0.f, 0.f};
        #pragma unroll
        for (int s = 0; s < 8; s++) {
            const int co = (((s * 4 + quad) ^ xr) << 3);
            hfrag a0 = *(const hfrag*)&Alds[aof0 + co];
            hfrag a1 = *(const hfrag*)&Alds[aof1 + co];
            hfrag b0 = *(const hfrag*)&bb[bof0 + co];
            hfrag b1f = *(const hfrag*)&bb[bof1 + co];
            acc[0][0] = __builtin_amdgcn_mfma_f32_16x16x32_f16(a0, b0, acc[0][0], 0, 0, 0);
            acc[0][1] = __builtin_amdgcn_mfma_f32_16x16x32_f16(a0, b1f, acc[0][1], 0, 0, 0);
            acc[1][0] = __builtin_amdgcn_mfma_f32_16x16x32_f16(a1, b0, acc[1][0], 0, 0, 0);
            acc[1][1] = __builtin_amdgcn_mfma_f32_16x16x32_f16(a1, b1f, acc[1][1], 0, 0, 0);
        }
        // partial logit: sum over this wave's 32 rows
        float s0 = 0.f, s1 = 0.f;
        #pragma unroll
        for (int dt = 0; dt < 2; dt++)
            #pragma unroll
            for (int r = 0; r < 4; r++) {
                float h0 = acc[dt][0][r] + b1v[dt][r];
                float h1 = acc[dt][1][r] + b1v[dt][r];
                h0 = h0 > 0.f ? h0 : 0.f;
                h1 = h1 > 0.f ? h1 : 0.f;
                s0 += w2v[dt][r] * h0;
                s1 += w2v[dt][r] * h1;
            }
        s0 += __shfl_xor(s0, 16); s0 += __shfl_xor(s0, 32);
        s1 += __shfl_xor(s1, 16); s1 += __shfl_xor(s1, 32);
        if (ln < 16) {
            red[ngr][mwv][ln]      = s0;
            red[ngr][mwv][16 + ln] = s1;
        }
        asm volatile("s_waitcnt lgkmcnt(0)" ::: "memory");
        __builtin_amdgcn_s_barrier();                  // red + bb reads done
        if (t < 64) {
            int g = t >> 5, i32 = t & 31;
            float v = red[g][0][i32] + red[g][1][i32] + red[g][2][i32] + red[g][3][i32];
            int pix = tp0 + t;
            if (pix < HW) hpo[pix] = v;
        }
        if (it + 1 < ntl) {
            if (it + 2 < ntl) {
                stageB(bx + (it + 2) * 30, (it & 1) ? Bl1 : Bl0);
                asm volatile("s_waitcnt vmcnt(4)" ::: "memory");
            } else {
                asm volatile("s_waitcnt vmcnt(0)" ::: "memory");
            }
            __builtin_amdgcn_s_barrier();
            __builtin_amdgcn_sched_barrier(0);
        }
    }
}

// ---------------------------------------------------------------------------
// K2b: heat = exp(hp0 + hp1 + b2[p])  (60800 elems)
// ---------------------------------------------------------------------------
__global__ __launch_bounds__(256)
void k_hexp(const float* __restrict__ hp, const float* __restrict__ b2,
            float* __restrict__ heat)
{
    int t4 = blockIdx.x * 256 + threadIdx.x;
    if (t4 >= (Bx * PTS * HW) / 4) return;
    int i = t4 * 4;
    float b2v = b2[(i / HW) & 1];
    float4 a = *(const float4*)(hp + i);
    float4 c = *(const float4*)(hp + (size_t)(Bx * PTS * HW) + i);
    float4 o;
    o.x = expf(a.x + c.x + b2v);
    o.y = expf(a.y + c.y + b2v);
    o.z = expf(a.z + c.z + b2v);
    o.w = expf(a.w + c.w + b2v);
    *(float4*)(heat + i) = o;
}

// ---------------------------------------------------------------------------
// K3: deformable sampling (unchanged from round 1)
// ---------------------------------------------------------------------------
__global__ __launch_bounds__(256)
void k_sample(const ushort* __restrict__ efp, const float* __restrict__ heat,
              const float* __restrict__ offs, ushort* __restrict__ outs)
{
    __shared__ uint2 s_wo[32][20];
    const int t = threadIdx.x;
    const int bid = blockIdx.x;
    const int nx = (bid & 7) * 60 + (bid >> 3);
    if (nx >= 475) return;
    const int m0 = nx * 32;
    const int p = blockIdx.y;
    const int b = blockIdx.z;
    const float* heat_bp = heat + (size_t)(b * PTS + p) * HW;

    if (t < 32 * BINS) {
        int j = t / BINS, k = t % BINS;
        int hw = m0 + j;
        int hh = hw / Ww, ww = hw % Ww;
        int chy = (p * BINS + k) * 2;
        float oy = offs[((size_t)b * (PTS * BINS * 2) + chy)     * HW + hw];
        float ox = offs[((size_t)b * (PTS * BINS * 2) + chy + 1) * HW + hw];
        float ysf = (float)hh + oy;
        float xsf = (float)ww + ox;
        float y0 = floorf(ysf), x0 = floorf(xsf);
        #pragma unroll
        for (int dy = 0; dy < 2; dy++)
            #pragma unroll
            for (int dx = 0; dx < 2; dx++) {
                float yi = y0 + dy, xi = x0 + dx;
                float wgt = (1.f - fabsf(ysf - yi)) * (1.f - fabsf(xsf - xi));
                bool valid = (yi >= 0.f) && (yi <= (float)(Hh - 1)) &&
                             (xi >= 0.f) && (xi <= (float)(Ww - 1));
                int yc = (int)yi; yc = yc < 0 ? 0 : (yc > Hh - 1 ? Hh - 1 : yc);
                int xc = (int)xi; xc = xc < 0 ? 0 : (xc > Ww - 1 ? Ww - 1 : xc);
                int idx = yc * Ww + xc;
                float wh = valid ? wgt * heat_bp[idx] : 0.f;
                s_wo[j][k * 4 + dy * 2 + dx] =
                    make_uint2(__float_as_uint(wh), (unsigned)idx << 9);
            }
    }
    __syncthreads();
    if (t < 32) {
        float s = 0.f;
        #pragma unroll
        for (int u = 0; u < 20; u++) s += __uint_as_float(s_wo[t][u].x);
        float inv = 1.f / (s + EPS_DIV);
        #pragma unroll
        for (int u = 0; u < 20; u++) {
            float w = __uint_as_float(s_wo[t][u].x) * inv;
            unsigned hw16 = (unsigned)f2h(w);
            s_wo[t][u].x = hw16 | (hw16 << 16);   // replicated fp16 pair
        }
    }
    __syncthreads();

    const int wv = t >> 6, ln = t & 63;
    const int half = ln >> 5, c8 = ln & 31;
    const char* efbase = (const char*)(efp + (size_t)((b * PTS + p) * HW) * Cc)
                         + c8 * 16;
    ushort* ob = outs + ((size_t)(b * HW + m0)) * (PTS * Cc) + p * Cc + c8 * 8;
    #pragma unroll
    for (int i = 0; i < 8; i += 2) {
        const int j = wv * 8 + i + half;
        h2 a0 = (h2){0, 0}, a1 = (h2){0, 0}, a2 = (h2){0, 0}, a3 = (h2){0, 0};
        #pragma unroll
        for (int u = 0; u < 20; u++) {
            uint2 wo = s_wo[j][u];
            uint4 v = *(const uint4*)(efbase + wo.y);
            h2 wp = __builtin_bit_cast(h2, wo.x);
            a0 += wp * __builtin_bit_cast(h2, v.x);
            a1 += wp * __builtin_bit_cast(h2, v.y);
            a2 += wp * __builtin_bit_cast(h2, v.z);
            a3 += wp * __builtin_bit_cast(h2, v.w);
        }
        uint4 o = { __builtin_bit_cast(unsigned, a0), __builtin_bit_cast(unsigned, a1),
                    __builtin_bit_cast(unsigned, a2), __builtin_bit_cast(unsigned, a3) };
        *(uint4*)(ob + (size_t)j * (PTS * Cc)) = o;
    }
}

// ---------------------------------------------------------------------------
// K4: mgb[b][c][pix] (fp16) = merge_w @ outs + merge_b (unchanged)
// ---------------------------------------------------------------------------
__global__ __launch_bounds__(256)
void k_merge(const ushort* __restrict__ outs, const ushort* __restrict__ wbm,
             const float* __restrict__ mb, ushort* __restrict__ mgb,
             float* __restrict__ part2)
{
    __shared__ ushort As[64 * 72];
    __shared__ ushort Bs[64 * 72];
    const int t = threadIdx.x;
    const int wv = t >> 6, ln = t & 63;
    const int quad = ln >> 4, l16 = ln & 15;
    const int pix0 = blockIdx.x * 64;
    const int n0 = blockIdx.y * 64;
    const int b = blockIdx.z;
    const ushort* ob = outs + (size_t)b * HW * (PTS * Cc);

    f32x4 acc[4];
    #pragma unroll
    for (int j = 0; j < 4; j++) acc[j] = (f32x4){0.f, 0.f, 0.f, 0.f};

    const int srow = t >> 3, scol = (t & 7) * 8;

    for (int k0 = 0; k0 < 512; k0 += 64) {
        #pragma unroll
        for (int r = 0; r < 2; r++) {
            int row = srow + r * 32;
            *(uint4*)&As[row * 72 + scol] =
                *(const uint4*)&wbm[(size_t)(n0 + row) * 512 + k0 + scol];
        }
        #pragma unroll
        for (int r = 0; r < 2; r++) {
            int row = srow + r * 32;
            int pq = pix0 + row; if (pq > HW - 1) pq = HW - 1;
            *(uint4*)&Bs[row * 72 + scol] =
                *(const uint4*)&ob[(size_t)pq * (PTS * Cc) + k0 + scol];
        }
        __syncthreads();
        #pragma unroll
        for (int kk = 0; kk < 64; kk += 32) {
            hfrag af = *(const hfrag*)&As[(wv * 16 + l16) * 72 + kk + quad * 8];
            #pragma unroll
            for (int pt = 0; pt < 4; pt++) {
                hfrag bfr = *(const hfrag*)&Bs[(pt * 16 + l16) * 72 + kk + quad * 8];
                acc[pt] = __builtin_amdgcn_mfma_f32_16x16x32_f16(
                    af, bfr, acc[pt], 0, 0, 0);
            }
        }
        __syncthreads();
    }

    const int ch = n0 + wv * 16 + quad * 4;
    float bias[4];
    #pragma unroll
    for (int r = 0; r < 4; r++) bias[r] = mb[ch + r];

    float sacc = 0.f, qacc = 0.f;
    #pragma unroll
    for (int pt = 0; pt < 4; pt++) {
        int pix = pix0 + pt * 16 + l16;
        if (pix < HW) {
            #pragma unroll
            for (int r = 0; r < 4; r++) {
                float v = acc[pt][r] + bias[r];
                mgb[((size_t)b * Cc + ch + r) * HW + pix] = f2h(v);
                sacc += v; qacc += v * v;
            }
        }
    }
    #pragma unroll
    for (int off = 1; off <= 16; off <<= 1) {
        sacc += __shfl_xor(sacc, off);
        qacc += __shfl_xor(qacc, off);
    }
    if ((ln & 31) == 0) {
        int g = (n0 >> 3) + wv * 2 + (quad >> 1);
        size_t idx = ((size_t)(b * 32 + g) * NTILE + blockIdx.x) * 2;
        part2[idx + 0] = sacc;
        part2[idx + 1] = qacc;
    }
}

// ---------------------------------------------------------------------------
// K5: reduce per-tile GN partials -> mean/istd per (b,group)
// ---------------------------------------------------------------------------
__global__ __launch_bounds__(256)
void k_gnfinal(const float* __restrict__ part2, float* __restrict__ statf)
{
    const int bg = blockIdx.x;
    const int t = threadIdx.x;
    float s = 0.f, q = 0.f;
    if (t < NTILE) {
        s = part2[((size_t)bg * NTILE + t) * 2 + 0];
        q = part2[((size_t)bg * NTILE + t) * 2 + 1];
    }
    #pragma unroll
    for (int off = 1; off <= 32; off <<= 1) {
        s += __shfl_xor(s, off);
        q += __shfl_xor(q, off);
    }
    __shared__ float rs[4], rq[4];
    int wid = t >> 6;
    if ((t & 63) == 0) { rs[wid] = s; rq[wid] = q; }
    __syncthreads();
    if (t == 0) {
        float S = rs[0] + rs[1] + rs[2] + rs[3];
        float Q = rq[0] + rq[1] + rq[2] + rq[3];
        const float n = 8.f * HW;
        float mean = S / n;
        float var  = Q / n - mean * mean;
        statf[bg * 2 + 0] = mean;
        statf[bg * 2 + 1] = rsqrtf(var + GN_EPS);
    }
}

// ---------------------------------------------------------------------------
// K6: apply GN scale/shift + ReLU
// ---------------------------------------------------------------------------
__global__ __launch_bounds__(256)
void k_gnapply(const ushort* __restrict__ mgb, const float* __restrict__ statf,
               const float* __restrict__ gg, const float* __restrict__ gb,
               float* __restrict__ out)
{
    const int i8 = blockIdx.x * 256 + threadIdx.x;
    const int i = i8 * 8;
    const int CHW = Cc * HW;
    const int b = i / CHW;
    const int r = i - b * CHW;
    const int c = r / HW;
    const int g = c >> 3;
    float mean = statf[(b * 32 + g) * 2 + 0];
    float istd = statf[(b * 32 + g) * 2 + 1];
    float sc = istd * gg[c];
    float sh = gb[c] - mean * sc;
    uint4 v = *(const uint4*)(mgb + i);
    float4 o0, o1;
    o0.x = fmaxf(hlo(v.x) * sc + sh, 0.f);
    o0.y = fmaxf(hhi(v.x) * sc + sh, 0.f);
    o0.z = fmaxf(hlo(v.y) * sc + sh, 0.f);
    o0.w = fmaxf(hhi(v.y) * sc + sh, 0.f);
    o1.x = fmaxf(hlo(v.z) * sc + sh, 0.f);
    o1.y = fmaxf(hhi(v.z) * sc + sh, 0.f);
    o1.z = fmaxf(hlo(v.w) * sc + sh, 0.f);
    o1.w = fmaxf(hhi(v.w) * sc + sh, 0.f);
    *(float4*)(out + i)     = o0;
    *(float4*)(out + i + 4) = o1;
}

// ---------------------------------------------------------------------------
extern "C" void kernel_launch(void* const* d_in, const int* in_sizes, int n_in,
                              void* d_out, int out_size, void* d_ws, size_t ws_size,
                              hipStream_t stream)
{
    const float* x    = (const float*)d_in[0];
    const float* offs = (const float*)d_in[1];
    const float* efw  = (const float*)d_in[2];
    const float* efb  = (const float*)d_in[3];
    const float* w1   = (const float*)d_in[4];
    const float* b1   = (const float*)d_in[5];
    const float* w2   = (const float*)d_in[6];
    const float* b2   = (const float*)d_in[7];
    const float* mw   = (const float*)d_in[8];
    const float* mb   = (const float*)d_in[9];
    const float* gg   = (const float*)d_in[10];
    const float* gb   = (const float*)d_in[11];
    float* out = (float*)d_out;

    ushort* wb    = (ushort*)d_ws;
    ushort* wbe   = wb;                          // 131072
    ushort* wb1   = wb + 131072;
    ushort* wbm   = wb + 262144;
    ushort* efp   = wb + 393216;                        // B*P*HW*C fp16
    ushort* outsb = efp + (size_t)Bx * PTS * HW * Cc;   // B*HW*P*C fp16
    ushort* xbt   = outsb + (size_t)Bx * HW * PTS * Cc; // B*HW*C fp16
    ushort* mgb   = xbt + (size_t)Bx * HW * Cc;         // B*C*HW fp16
    float*  heat  = (float*)(mgb + (size_t)Bx * Cc * HW);
    float*  part2 = heat + (size_t)Bx * PTS * HW;       // 64*NTILE*2 floats
    float*  statf = part2 + (size_t)64 * NTILE * 2;     // 128 floats
    float*  hp    = statf + 128;                        // 2 * B*P*HW floats

    dim3 blk(256);
    k_wconv  <<<dim3(384),              blk, 0, stream>>>(efw, w1, mw, wb);
    k_xt     <<<dim3(475, 8, Bx),       blk, 0, stream>>>(x, xbt);
    k_ef     <<<dim3(30, 4, Bx),  dim3(512), 0, stream>>>(xbt, wbe, efb, efp);
    k_heat   <<<dim3(30, 4, Bx),  dim3(512), 0, stream>>>(efp, wb1, b1, w2, hp);
    k_hexp   <<<dim3(60),               blk, 0, stream>>>(hp, b2, heat);
    k_sample <<<dim3(480, PTS, Bx),     blk, 0, stream>>>(efp, heat, offs, outsb);
    k_merge  <<<dim3(NTILE, 4, Bx),     blk, 0, stream>>>(outsb, wbm, mb, mgb, part2);
    k_gnfinal<<<dim3(64),               blk, 0, stream>>>(part2, statf);
    k_gnapply<<<dim3(Bx * Cc * HW / 8 / 256), blk, 0, stream>>>(mgb, statf, gg, gb, out);
}

// Round 3
// 206.294 us; speedup vs baseline: 1.0147x; 1.0147x over previous
//
#include <hip/hip_runtime.h>

#define BINS 5
#define PTS  2
constexpr int Bx = 2, Cc = 256, Hh = 100, Ww = 152;
constexpr int HW = Hh * Ww;          // 15200
constexpr int NTILE = 238;           // 64-px tiles
constexpr float EPS_DIV = 1e-6f;
constexpr float GN_EPS  = 1e-5f;

typedef __attribute__((ext_vector_type(8)))  _Float16 hfrag;  // 8 fp16
typedef __attribute__((ext_vector_type(2)))  _Float16 h2;
typedef __attribute__((ext_vector_type(16))) float    f32x16; // 32x32 MFMA C/D

__device__ __forceinline__ ushort f2h(float f) {
    return __builtin_bit_cast(ushort, (_Float16)f);
}
__device__ __forceinline__ float hlo(unsigned u) {
    return (float)__builtin_bit_cast(_Float16, (ushort)(u & 0xffffu));
}
__device__ __forceinline__ float hhi(unsigned u) {
    return (float)__builtin_bit_cast(_Float16, (ushort)(u >> 16));
}

#define GLL16(g, l) __builtin_amdgcn_global_load_lds( \
    (const __attribute__((address_space(1))) unsigned*)(g), \
    (__attribute__((address_space(3))) unsigned*)(l), 16, 0, 0)

#define MFMA32(a, b, c) __builtin_amdgcn_mfma_f32_32x32x16_f16(a, b, c, 0, 0, 0)

// ---------------------------------------------------------------------------
// K0: convert weights to fp16 in 32x32x16-MFMA fragment order.
// For [M][K]: elem(m,k) -> (((k>>4)*(M/32) + (m>>5))*64 + (m&31) + 32*((k>>3)&1))*8 + (k&7)
// so a wave's A-frag load (lane ln) is one coalesced 1KB dwordx4 burst.
// ---------------------------------------------------------------------------
__global__ __launch_bounds__(256)
void k_wconv(const float* __restrict__ efw, const float* __restrict__ w1,
             const float* __restrict__ mw, ushort* __restrict__ wb)
{
    int gid = blockIdx.x * 256 + threadIdx.x;     // 192 blocks
    int i = gid * 8;
    int arr = i >> 17, off = i & 131071;
    const float* src = arr == 0 ? efw : (arr == 1 ? w1 : mw);
    float4 v0 = *(const float4*)(src + off);
    float4 v1 = *(const float4*)(src + off + 4);
    int outaddr;
    if (arr == 0) {                // ef_w: M=512, K=256, M/32=16
        int m = off >> 8, k = off & 255;
        outaddr = (((k >> 4) * 16 + (m >> 5)) * 64 + (m & 31) + 32 * ((k >> 3) & 1)) * 8;
    } else if (arr == 1) {         // hm1_w: per p, M=256, K=256, M/32=8
        int p = off >> 16, r = off & 65535;
        int m = r >> 8, k = r & 255;
        outaddr = p * 65536 +
                  (((k >> 4) * 8 + (m >> 5)) * 64 + (m & 31) + 32 * ((k >> 3) & 1)) * 8;
    } else {                       // merge_w: M=256, K=512, M/32=8
        int m = off >> 9, k = off & 511;
        outaddr = (((k >> 4) * 8 + (m >> 5)) * 64 + (m & 31) + 32 * ((k >> 3) & 1)) * 8;
    }
    ushort o[8] = { f2h(v0.x), f2h(v0.y), f2h(v0.z), f2h(v0.w),
                    f2h(v1.x), f2h(v1.y), f2h(v1.z), f2h(v1.w) };
    *(uint4*)(wb + arr * 131072 + outaddr) = *(uint4*)o;
}

// ---------------------------------------------------------------------------
// K0b: transpose+convert x[b][c][hw] fp32 -> xbt[b][hw][c] fp16
// ---------------------------------------------------------------------------
__global__ __launch_bounds__(256)
void k_xt(const float* __restrict__ x, ushort* __restrict__ xbt)
{
    __shared__ float tile[32][33];
    const int t = threadIdx.x;
    const int hw0 = blockIdx.x * 32;
    const int c0 = blockIdx.y * 32;
    const int b = blockIdx.z;
    const float* xb = x + ((size_t)b * Cc + c0) * HW + hw0;
    const int tx = t & 31, ty = t >> 5;
    #pragma unroll
    for (int r = 0; r < 4; r++) {
        int c = ty + r * 8;
        tile[c][tx] = xb[(size_t)c * HW + tx];
    }
    __syncthreads();
    const int hwl = t >> 3, c4 = (t & 7) * 4;
    ushort4 o = { f2h(tile[c4 + 0][hwl]), f2h(tile[c4 + 1][hwl]),
                  f2h(tile[c4 + 2][hwl]), f2h(tile[c4 + 3][hwl]) };
    *(ushort4*)&xbt[((size_t)b * HW + hw0 + hwl) * Cc + c0 + c4] = o;
}

// ---------------------------------------------------------------------------
// K1: efp = ef_w @ x + ef_b.  A (512x256) in registers (frag-order, 2 mf x
// 16 ks per wave), LDS = B only (2 x 32KB dbuf).  32x32x16 MFMA, 2x2 acc.
// Fixed 2 tiles per block, counted vmcnt.
// ---------------------------------------------------------------------------
__global__ __launch_bounds__(512, 2)
void k_ef(const ushort* __restrict__ xbt, const ushort* __restrict__ wbe,
          const float* __restrict__ efb, ushort* __restrict__ efp)
{
    __shared__ ushort B0[64 * 256];
    __shared__ ushort B1[64 * 256];
    const int t = threadIdx.x;
    const int wv = t >> 6, ln = t & 63;
    const int l31 = ln & 31, lh = ln >> 5;
    const int b = blockIdx.y;
    const int tt0 = blockIdx.x * 2;
    const ushort* xb = xbt + (size_t)b * HW * Cc;

    hfrag A[2][16];
    #pragma unroll
    for (int mf = 0; mf < 2; mf++)
        #pragma unroll
        for (int ks = 0; ks < 16; ks++)
            A[mf][ks] = *(const hfrag*)&wbe[((ks * 16 + (wv * 2 + mf)) * 64 + ln) * 8];
    __builtin_amdgcn_sched_barrier(0);

    auto stageB = [&](int tt, ushort* dst) {
        int tp0 = tt * 64;
        #pragma unroll
        for (int j = 0; j < 4; j++) {
            int unit = j * 512 + t;
            int prow = unit >> 5, c8 = unit & 31;
            int pq = tp0 + prow; if (pq > HW - 1) pq = HW - 1;
            const ushort* g = xb + (size_t)pq * Cc + ((c8 ^ (prow & 7)) << 3);
            ushort* l = dst + (j * 512 + wv * 64) * 8;
            GLL16(g, l);
        }
    };
    stageB(tt0, B0);
    stageB(tt0 + 1, B1);
    __builtin_amdgcn_sched_barrier(0);
    asm volatile("s_waitcnt vmcnt(4)" ::: "memory");   // A + B0 complete
    __builtin_amdgcn_s_barrier();
    __builtin_amdgcn_sched_barrier(0);

    auto compute = [&](int tt, const ushort* Bs) {
        f32x16 acc[2][2];
        #pragma unroll
        for (int mf = 0; mf < 2; mf++)
            #pragma unroll
            for (int pf = 0; pf < 2; pf++)
                #pragma unroll
                for (int r = 0; r < 16; r++) acc[mf][pf][r] = 0.f;
        #pragma unroll
        for (int ks = 0; ks < 16; ks++) {
            int c = ks * 2 + lh;
            #pragma unroll
            for (int pf = 0; pf < 2; pf++) {
                hfrag bf = *(const hfrag*)&Bs[(pf * 32 + l31) * 256 + ((c ^ (l31 & 7)) << 3)];
                acc[0][pf] = MFMA32(A[0][ks], bf, acc[0][pf]);
                acc[1][pf] = MFMA32(A[1][ks], bf, acc[1][pf]);
            }
        }
        const int tp0 = tt * 64;
        const int p_ = wv >> 2;
        ushort* outb = efp + (size_t)((b * PTS + p_) * HW) * Cc;
        #pragma unroll
        for (int mf = 0; mf < 2; mf++) {
            int m0 = wv * 2 + mf;
            int chb = (m0 * 32) & 255;
            #pragma unroll
            for (int q = 0; q < 4; q++) {
                float4 bv = *(const float4*)&efb[m0 * 32 + q * 8 + 4 * lh];
                #pragma unroll
                for (int pf = 0; pf < 2; pf++) {
                    int px = tp0 + pf * 32 + l31;
                    if (px < HW) {
                        int ch = chb + q * 8 + 4 * lh;
                        ushort4 o = { f2h(acc[mf][pf][q * 4 + 0] + bv.x),
                                      f2h(acc[mf][pf][q * 4 + 1] + bv.y),
                                      f2h(acc[mf][pf][q * 4 + 2] + bv.z),
                                      f2h(acc[mf][pf][q * 4 + 3] + bv.w) };
                        *(ushort4*)&outb[(size_t)px * Cc + ch] = o;
                    }
                }
            }
        }
    };
    compute(tt0, B0);
    asm volatile("s_waitcnt vmcnt(0)" ::: "memory");   // B1 (and stores) done
    __builtin_amdgcn_s_barrier();
    __builtin_amdgcn_sched_barrier(0);
    compute(tt0 + 1, B1);
}

// ---------------------------------------------------------------------------
// K2: heat = exp(w2.relu(w1@efp + b1) + b2) fused: full M=256 per block ->
// complete logit reduced in-block, exp inline.  A (256x256 per p) in regs.
// ---------------------------------------------------------------------------
__global__ __launch_bounds__(512, 2)
void k_heat(const ushort* __restrict__ efp, const ushort* __restrict__ wb1,
            const float* __restrict__ b1, const float* __restrict__ w2,
            const float* __restrict__ b2, float* __restrict__ heat)
{
    __shared__ ushort B0[64 * 256];
    __shared__ ushort B1[64 * 256];
    __shared__ float red[8][64];
    const int t = threadIdx.x;
    const int wv = t >> 6, ln = t & 63;
    const int l31 = ln & 31, lh = ln >> 5;
    const int zz = blockIdx.y;
    const int b = zz >> 1, p = zz & 1;
    const int tt0 = blockIdx.x * 2;
    const ushort* eb = efp + (size_t)((b * PTS + p) * HW) * Cc;
    const float* b1p = b1 + p * 256;
    const float* w2p = w2 + p * 256;
    const float b2v = b2[p];

    hfrag A[16];
    #pragma unroll
    for (int ks = 0; ks < 16; ks++)
        A[ks] = *(const hfrag*)&wb1[p * 65536 + ((ks * 8 + wv) * 64 + ln) * 8];
    __builtin_amdgcn_sched_barrier(0);

    auto stageB = [&](int tt, ushort* dst) {
        int tp0 = tt * 64;
        #pragma unroll
        for (int j = 0; j < 4; j++) {
            int unit = j * 512 + t;
            int prow = unit >> 5, c8 = unit & 31;
            int pq = tp0 + prow; if (pq > HW - 1) pq = HW - 1;
            const ushort* g = eb + (size_t)pq * Cc + ((c8 ^ (prow & 7)) << 3);
            ushort* l = dst + (j * 512 + wv * 64) * 8;
            GLL16(g, l);
        }
    };
    stageB(tt0, B0);
    stageB(tt0 + 1, B1);
    __builtin_amdgcn_sched_barrier(0);
    asm volatile("s_waitcnt vmcnt(4)" ::: "memory");
    __builtin_amdgcn_s_barrier();
    __builtin_amdgcn_sched_barrier(0);

    auto compute = [&](int tt, const ushort* Bs) {
        f32x16 acc[2];
        #pragma unroll
        for (int pf = 0; pf < 2; pf++)
            #pragma unroll
            for (int r = 0; r < 16; r++) acc[pf][r] = 0.f;
        #pragma unroll
        for (int ks = 0; ks < 16; ks++) {
            int c = ks * 2 + lh;
            #pragma unroll
            for (int pf = 0; pf < 2; pf++) {
                hfrag bf = *(const hfrag*)&Bs[(pf * 32 + l31) * 256 + ((c ^ (l31 & 7)) << 3)];
                acc[pf] = MFMA32(A[ks], bf, acc[pf]);
            }
        }
        // partial logit over this wave's 32 rows
        float s[2] = {0.f, 0.f};
        #pragma unroll
        for (int q = 0; q < 4; q++) {
            float4 b1v = *(const float4*)&b1p[wv * 32 + q * 8 + 4 * lh];
            float4 w2v = *(const float4*)&w2p[wv * 32 + q * 8 + 4 * lh];
            #pragma unroll
            for (int pf = 0; pf < 2; pf++) {
                float h0 = acc[pf][q * 4 + 0] + b1v.x;
                float h1 = acc[pf][q * 4 + 1] + b1v.y;
                float h2_ = acc[pf][q * 4 + 2] + b1v.z;
                float h3 = acc[pf][q * 4 + 3] + b1v.w;
                s[pf] += w2v.x * (h0 > 0.f ? h0 : 0.f);
                s[pf] += w2v.y * (h1 > 0.f ? h1 : 0.f);
                s[pf] += w2v.z * (h2_ > 0.f ? h2_ : 0.f);
                s[pf] += w2v.w * (h3 > 0.f ? h3 : 0.f);
            }
        }
        s[0] += __shfl_xor(s[0], 32);
        s[1] += __shfl_xor(s[1], 32);
        if (lh == 0) {
            red[wv][l31]      = s[0];
            red[wv][32 + l31] = s[1];
        }
        asm volatile("s_waitcnt lgkmcnt(0)" ::: "memory");
        __builtin_amdgcn_s_barrier();
        if (t < 64) {
            float v = red[0][t] + red[1][t] + red[2][t] + red[3][t] +
                      red[4][t] + red[5][t] + red[6][t] + red[7][t];
            int px = tt * 64 + t;
            if (px < HW) heat[(size_t)(b * PTS + p) * HW + px] = expf(v + b2v);
        }
    };
    compute(tt0, B0);
    asm volatile("s_waitcnt vmcnt(0)" ::: "memory");
    __builtin_amdgcn_s_barrier();
    __builtin_amdgcn_sched_barrier(0);
    compute(tt0 + 1, B1);
}

// ---------------------------------------------------------------------------
// K3: deformable sampling (unchanged; fp16 packed-FMA inner loop)
// ---------------------------------------------------------------------------
__global__ __launch_bounds__(256)
void k_sample(const ushort* __restrict__ efp, const float* __restrict__ heat,
              const float* __restrict__ offs, ushort* __restrict__ outs)
{
    __shared__ uint2 s_wo[32][20];
    const int t = threadIdx.x;
    const int bid = blockIdx.x;
    const int nx = (bid & 7) * 60 + (bid >> 3);
    if (nx >= 475) return;
    const int m0 = nx * 32;
    const int p = blockIdx.y;
    const int b = blockIdx.z;
    const float* heat_bp = heat + (size_t)(b * PTS + p) * HW;

    if (t < 32 * BINS) {
        int j = t / BINS, k = t % BINS;
        int hw = m0 + j;
        int hh = hw / Ww, ww = hw % Ww;
        int chy = (p * BINS + k) * 2;
        float oy = offs[((size_t)b * (PTS * BINS * 2) + chy)     * HW + hw];
        float ox = offs[((size_t)b * (PTS * BINS * 2) + chy + 1) * HW + hw];
        float ysf = (float)hh + oy;
        float xsf = (float)ww + ox;
        float y0 = floorf(ysf), x0 = floorf(xsf);
        #pragma unroll
        for (int dy = 0; dy < 2; dy++)
            #pragma unroll
            for (int dx = 0; dx < 2; dx++) {
                float yi = y0 + dy, xi = x0 + dx;
                float wgt = (1.f - fabsf(ysf - yi)) * (1.f - fabsf(xsf - xi));
                bool valid = (yi >= 0.f) && (yi <= (float)(Hh - 1)) &&
                             (xi >= 0.f) && (xi <= (float)(Ww - 1));
                int yc = (int)yi; yc = yc < 0 ? 0 : (yc > Hh - 1 ? Hh - 1 : yc);
                int xc = (int)xi; xc = xc < 0 ? 0 : (xc > Ww - 1 ? Ww - 1 : xc);
                int idx = yc * Ww + xc;
                float wh = valid ? wgt * heat_bp[idx] : 0.f;
                s_wo[j][k * 4 + dy * 2 + dx] =
                    make_uint2(__float_as_uint(wh), (unsigned)idx << 9);
            }
    }
    __syncthreads();
    if (t < 32) {
        float s = 0.f;
        #pragma unroll
        for (int u = 0; u < 20; u++) s += __uint_as_float(s_wo[t][u].x);
        float inv = 1.f / (s + EPS_DIV);
        #pragma unroll
        for (int u = 0; u < 20; u++) {
            float w = __uint_as_float(s_wo[t][u].x) * inv;
            unsigned hw16 = (unsigned)f2h(w);
            s_wo[t][u].x = hw16 | (hw16 << 16);
        }
    }
    __syncthreads();

    const int wv = t >> 6, ln = t & 63;
    const int half = ln >> 5, c8 = ln & 31;
    const char* efbase = (const char*)(efp + (size_t)((b * PTS + p) * HW) * Cc)
                         + c8 * 16;
    ushort* ob = outs + ((size_t)(b * HW + m0)) * (PTS * Cc) + p * Cc + c8 * 8;
    #pragma unroll
    for (int i = 0; i < 8; i += 2) {
        const int j = wv * 8 + i + half;
        h2 a0 = (h2){0, 0}, a1 = (h2){0, 0}, a2 = (h2){0, 0}, a3 = (h2){0, 0};
        #pragma unroll
        for (int u = 0; u < 20; u++) {
            uint2 wo = s_wo[j][u];
            uint4 v = *(const uint4*)(efbase + wo.y);
            h2 wp = __builtin_bit_cast(h2, wo.x);
            a0 += wp * __builtin_bit_cast(h2, v.x);
            a1 += wp * __builtin_bit_cast(h2, v.y);
            a2 += wp * __builtin_bit_cast(h2, v.z);
            a3 += wp * __builtin_bit_cast(h2, v.w);
        }
        uint4 o = { __builtin_bit_cast(unsigned, a0), __builtin_bit_cast(unsigned, a1),
                    __builtin_bit_cast(unsigned, a2), __builtin_bit_cast(unsigned, a3) };
        *(uint4*)(ob + (size_t)j * (PTS * Cc)) = o;
    }
}

// ---------------------------------------------------------------------------
// K4: mgb = merge_w @ outs + merge_b.  Full M=256 per block (A in regs,
// 32 ks), outs read ONCE.  B tile 64px x 512 (64KB x2 dbuf).
// ---------------------------------------------------------------------------
__global__ __launch_bounds__(512, 2)
void k_merge(const ushort* __restrict__ outs, const ushort* __restrict__ wbm,
             const float* __restrict__ mb, ushort* __restrict__ mgb,
             float* __restrict__ part2)
{
    __shared__ ushort B0[64 * 512];
    __shared__ ushort B1[64 * 512];
    const int t = threadIdx.x;
    const int wv = t >> 6, ln = t & 63;
    const int l31 = ln & 31, lh = ln >> 5;
    const int b = blockIdx.y;
    const int tt0 = blockIdx.x * 2;
    const ushort* ob = outs + (size_t)b * HW * (PTS * Cc);

    hfrag A[32];
    #pragma unroll
    for (int ks = 0; ks < 32; ks++)
        A[ks] = *(const hfrag*)&wbm[((ks * 8 + wv) * 64 + ln) * 8];
    __builtin_amdgcn_sched_barrier(0);

    auto stageB = [&](int tt, ushort* dst) {
        int tp0 = tt * 64;
        #pragma unroll
        for (int j = 0; j < 8; j++) {
            int unit = j * 512 + t;
            int prow = unit >> 6, c8 = unit & 63;
            int pq = tp0 + prow; if (pq > HW - 1) pq = HW - 1;
            const ushort* g = ob + (size_t)pq * (PTS * Cc) + ((c8 ^ (prow & 7)) << 3);
            ushort* l = dst + (j * 512 + wv * 64) * 8;
            GLL16(g, l);
        }
    };
    stageB(tt0, B0);
    stageB(tt0 + 1, B1);
    __builtin_amdgcn_sched_barrier(0);
    asm volatile("s_waitcnt vmcnt(8)" ::: "memory");   // A + B0 complete
    __builtin_amdgcn_s_barrier();
    __builtin_amdgcn_sched_barrier(0);

    auto compute = [&](int tt, const ushort* Bs) {
        f32x16 acc[2];
        #pragma unroll
        for (int pf = 0; pf < 2; pf++)
            #pragma unroll
            for (int r = 0; r < 16; r++) acc[pf][r] = 0.f;
        #pragma unroll
        for (int ks = 0; ks < 32; ks++) {
            int c = ks * 2 + lh;
            #pragma unroll
            for (int pf = 0; pf < 2; pf++) {
                hfrag bf = *(const hfrag*)&Bs[(pf * 32 + l31) * 512 + ((c ^ (l31 & 7)) << 3)];
                acc[pf] = MFMA32(A[ks], bf, acc[pf]);
            }
        }
        const int tp0 = tt * 64;
        float sg[4] = {0.f, 0.f, 0.f, 0.f};
        float qg[4] = {0.f, 0.f, 0.f, 0.f};
        #pragma unroll
        for (int q = 0; q < 4; q++) {
            float4 bv = *(const float4*)&mb[wv * 32 + q * 8 + 4 * lh];
            #pragma unroll
            for (int pf = 0; pf < 2; pf++) {
                int px = tp0 + pf * 32 + l31;
                if (px < HW) {
                    #pragma unroll
                    for (int r = 0; r < 4; r++) {
                        float bb = r == 0 ? bv.x : (r == 1 ? bv.y : (r == 2 ? bv.z : bv.w));
                        float v = acc[pf][q * 4 + r] + bb;
                        int ch = wv * 32 + q * 8 + 4 * lh + r;
                        mgb[((size_t)b * Cc + ch) * HW + px] = f2h(v);
                        sg[q] += v; qg[q] += v * v;
                    }
                }
            }
        }
        #pragma unroll
        for (int q = 0; q < 4; q++) {
            #pragma unroll
            for (int off = 1; off <= 32; off <<= 1) {
                sg[q] += __shfl_xor(sg[q], off);
                qg[q] += __shfl_xor(qg[q], off);
            }
        }
        if (ln == 0) {
            #pragma unroll
            for (int q = 0; q < 4; q++) {
                int g = wv * 4 + q;
                size_t idx = ((size_t)(b * 32 + g) * NTILE + tt) * 2;
                part2[idx + 0] = sg[q];
                part2[idx + 1] = qg[q];
            }
        }
    };
    compute(tt0, B0);
    asm volatile("s_waitcnt vmcnt(0)" ::: "memory");
    __builtin_amdgcn_s_barrier();
    __builtin_amdgcn_sched_barrier(0);
    compute(tt0 + 1, B1);
}

// ---------------------------------------------------------------------------
// K5: reduce per-tile GN partials -> mean/istd per (b,group)
// ---------------------------------------------------------------------------
__global__ __launch_bounds__(256)
void k_gnfinal(const float* __restrict__ part2, float* __restrict__ statf)
{
    const int bg = blockIdx.x;
    const int t = threadIdx.x;
    float s = 0.f, q = 0.f;
    if (t < NTILE) {
        s = part2[((size_t)bg * NTILE + t) * 2 + 0];
        q = part2[((size_t)bg * NTILE + t) * 2 + 1];
    }
    #pragma unroll
    for (int off = 1; off <= 32; off <<= 1) {
        s += __shfl_xor(s, off);
        q += __shfl_xor(q, off);
    }
    __shared__ float rs[4], rq[4];
    int wid = t >> 6;
    if ((t & 63) == 0) { rs[wid] = s; rq[wid] = q; }
    __syncthreads();
    if (t == 0) {
        float S = rs[0] + rs[1] + rs[2] + rs[3];
        float Q = rq[0] + rq[1] + rq[2] + rq[3];
        const float n = 8.f * HW;
        float mean = S / n;
        float var  = Q / n - mean * mean;
        statf[bg * 2 + 0] = mean;
        statf[bg * 2 + 1] = rsqrtf(var + GN_EPS);
    }
}

// ---------------------------------------------------------------------------
// K6: apply GN scale/shift + ReLU
// ---------------------------------------------------------------------------
__global__ __launch_bounds__(256)
void k_gnapply(const ushort* __restrict__ mgb, const float* __restrict__ statf,
               const float* __restrict__ gg, const float* __restrict__ gb,
               float* __restrict__ out)
{
    const int i8 = blockIdx.x * 256 + threadIdx.x;
    const int i = i8 * 8;
    const int CHW = Cc * HW;
    const int b = i / CHW;
    const int r = i - b * CHW;
    const int c = r / HW;
    const int g = c >> 3;
    float mean = statf[(b * 32 + g) * 2 + 0];
    float istd = statf[(b * 32 + g) * 2 + 1];
    float sc = istd * gg[c];
    float sh = gb[c] - mean * sc;
    uint4 v = *(const uint4*)(mgb + i);
    float4 o0, o1;
    o0.x = fmaxf(hlo(v.x) * sc + sh, 0.f);
    o0.y = fmaxf(hhi(v.x) * sc + sh, 0.f);
    o0.z = fmaxf(hlo(v.y) * sc + sh, 0.f);
    o0.w = fmaxf(hhi(v.y) * sc + sh, 0.f);
    o1.x = fmaxf(hlo(v.z) * sc + sh, 0.f);
    o1.y = fmaxf(hhi(v.z) * sc + sh, 0.f);
    o1.z = fmaxf(hlo(v.w) * sc + sh, 0.f);
    o1.w = fmaxf(hhi(v.w) * sc + sh, 0.f);
    *(float4*)(out + i)     = o0;
    *(float4*)(out + i + 4) = o1;
}

// ---------------------------------------------------------------------------
extern "C" void kernel_launch(void* const* d_in, const int* in_sizes, int n_in,
                              void* d_out, int out_size, void* d_ws, size_t ws_size,
                              hipStream_t stream)
{
    const float* x    = (const float*)d_in[0];
    const float* offs = (const float*)d_in[1];
    const float* efw  = (const float*)d_in[2];
    const float* efb  = (const float*)d_in[3];
    const float* w1   = (const float*)d_in[4];
    const float* b1   = (const float*)d_in[5];
    const float* w2   = (const float*)d_in[6];
    const float* b2   = (const float*)d_in[7];
    const float* mw   = (const float*)d_in[8];
    const float* mb   = (const float*)d_in[9];
    const float* gg   = (const float*)d_in[10];
    const float* gb   = (const float*)d_in[11];
    float* out = (float*)d_out;

    ushort* wb    = (ushort*)d_ws;
    ushort* wbe   = wb;                          // 131072 (frag order)
    ushort* wb1   = wb + 131072;
    ushort* wbm   = wb + 262144;
    ushort* efp   = wb + 393216;                        // B*P*HW*C fp16
    ushort* outsb = efp + (size_t)Bx * PTS * HW * Cc;   // B*HW*P*C fp16
    ushort* xbt   = outsb + (size_t)Bx * HW * PTS * Cc; // B*HW*C fp16
    ushort* mgb   = xbt + (size_t)Bx * HW * Cc;         // B*C*HW fp16
    float*  heat  = (float*)(mgb + (size_t)Bx * Cc * HW);
    float*  part2 = heat + (size_t)Bx * PTS * HW;       // 64*NTILE*2 floats
    float*  statf = part2 + (size_t)64 * NTILE * 2;     // 128 floats

    dim3 blk(256);
    k_wconv  <<<dim3(192),              blk, 0, stream>>>(efw, w1, mw, wb);
    k_xt     <<<dim3(475, 8, Bx),       blk, 0, stream>>>(x, xbt);
    k_ef     <<<dim3(119, Bx),    dim3(512), 0, stream>>>(xbt, wbe, efb, efp);
    k_heat   <<<dim3(119, 4),     dim3(512), 0, stream>>>(efp, wb1, b1, w2, b2, heat);
    k_sample <<<dim3(480, PTS, Bx),     blk, 0, stream>>>(efp, heat, offs, outsb);
    k_merge  <<<dim3(119, Bx),    dim3(512), 0, stream>>>(outsb, wbm, mb, mgb, part2);
    k_gnfinal<<<dim3(64),               blk, 0, stream>>>(part2, statf);
    k_gnapply<<<dim3(Bx * Cc * HW / 8 / 256), blk, 0, stream>>>(mgb, statf, gg, gb, out);
}

// Round 4
// 198.225 us; speedup vs baseline: 1.0560x; 1.0407x over previous
//
#include <hip/hip_runtime.h>

#define BINS 5
#define PTS  2
constexpr int Bx = 2, Cc = 256, Hh = 100, Ww = 152;
constexpr int HW = Hh * Ww;          // 15200
constexpr int NTILE = 238;           // 64-px tiles
constexpr float EPS_DIV = 1e-6f;
constexpr float GN_EPS  = 1e-5f;

typedef __attribute__((ext_vector_type(8)))  _Float16 hfrag;  // 8 fp16
typedef __attribute__((ext_vector_type(2)))  _Float16 h2;
typedef __attribute__((ext_vector_type(16))) float    f32x16; // 32x32 MFMA C/D

__device__ __forceinline__ ushort f2h(float f) {
    return __builtin_bit_cast(ushort, (_Float16)f);
}
__device__ __forceinline__ float hlo(unsigned u) {
    return (float)__builtin_bit_cast(_Float16, (ushort)(u & 0xffffu));
}
__device__ __forceinline__ float hhi(unsigned u) {
    return (float)__builtin_bit_cast(_Float16, (ushort)(u >> 16));
}

#define GLL16(g, l) __builtin_amdgcn_global_load_lds( \
    (const __attribute__((address_space(1))) unsigned*)(g), \
    (__attribute__((address_space(3))) unsigned*)(l), 16, 0, 0)

#define MFMA32(a, b, c) __builtin_amdgcn_mfma_f32_32x32x16_f16(a, b, c, 0, 0, 0)

// ---------------------------------------------------------------------------
// K0: fused preprocessing.  Blocks 0..191: weight convert to fp16 in
// 32x32x16-MFMA fragment order.  Blocks 192..7791: x transpose+convert.
// ---------------------------------------------------------------------------
__global__ __launch_bounds__(256)
void k_pre(const float* __restrict__ efw, const float* __restrict__ w1,
           const float* __restrict__ mw, ushort* __restrict__ wb,
           const float* __restrict__ x, ushort* __restrict__ xbt)
{
    __shared__ float tile[32][33];
    const int bid = blockIdx.x;
    const int t = threadIdx.x;
    if (bid < 192) {
        int gid = bid * 256 + t;
        int i = gid * 8;
        int arr = i >> 17, off = i & 131071;
        const float* src = arr == 0 ? efw : (arr == 1 ? w1 : mw);
        float4 v0 = *(const float4*)(src + off);
        float4 v1 = *(const float4*)(src + off + 4);
        int outaddr;
        if (arr == 0) {                // ef_w: M=512, K=256
            int m = off >> 8, k = off & 255;
            outaddr = (((k >> 4) * 16 + (m >> 5)) * 64 + (m & 31) + 32 * ((k >> 3) & 1)) * 8;
        } else if (arr == 1) {         // hm1_w: per p, M=256, K=256
            int p = off >> 16, r = off & 65535;
            int m = r >> 8, k = r & 255;
            outaddr = p * 65536 +
                      (((k >> 4) * 8 + (m >> 5)) * 64 + (m & 31) + 32 * ((k >> 3) & 1)) * 8;
        } else {                       // merge_w: M=256, K=512
            int m = off >> 9, k = off & 511;
            outaddr = (((k >> 4) * 8 + (m >> 5)) * 64 + (m & 31) + 32 * ((k >> 3) & 1)) * 8;
        }
        ushort o[8] = { f2h(v0.x), f2h(v0.y), f2h(v0.z), f2h(v0.w),
                        f2h(v1.x), f2h(v1.y), f2h(v1.z), f2h(v1.w) };
        *(uint4*)(wb + arr * 131072 + outaddr) = *(uint4*)o;
    } else {
        int r = bid - 192;             // 0..7599
        const int b = r / 3800; r -= b * 3800;
        const int c0 = (r / 475) * 32;
        const int hw0 = (r % 475) * 32;
        const float* xb = x + ((size_t)b * Cc + c0) * HW + hw0;
        const int tx = t & 31, ty = t >> 5;
        #pragma unroll
        for (int rr = 0; rr < 4; rr++) {
            int c = ty + rr * 8;
            tile[c][tx] = xb[(size_t)c * HW + tx];
        }
        __syncthreads();
        const int hwl = t >> 3, c4 = (t & 7) * 4;
        ushort4 o = { f2h(tile[c4 + 0][hwl]), f2h(tile[c4 + 1][hwl]),
                      f2h(tile[c4 + 2][hwl]), f2h(tile[c4 + 3][hwl]) };
        *(ushort4*)&xbt[((size_t)b * HW + hw0 + hwl) * Cc + c0 + c4] = o;
    }
}

// ---------------------------------------------------------------------------
// K1: efp = ef_w @ x + ef_b.  A (512x256) in registers, LDS = B only
// (2 x 32KB dbuf), 32x32x16 MFMA, counted vmcnt.  (proven R3)
// ---------------------------------------------------------------------------
__global__ __launch_bounds__(512, 2)
void k_ef(const ushort* __restrict__ xbt, const ushort* __restrict__ wbe,
          const float* __restrict__ efb, ushort* __restrict__ efp)
{
    __shared__ ushort B0[64 * 256];
    __shared__ ushort B1[64 * 256];
    const int t = threadIdx.x;
    const int wv = t >> 6, ln = t & 63;
    const int l31 = ln & 31, lh = ln >> 5;
    const int b = blockIdx.y;
    const int tt0 = blockIdx.x * 2;
    const ushort* xb = xbt + (size_t)b * HW * Cc;

    hfrag A[2][16];
    #pragma unroll
    for (int mf = 0; mf < 2; mf++)
        #pragma unroll
        for (int ks = 0; ks < 16; ks++)
            A[mf][ks] = *(const hfrag*)&wbe[((ks * 16 + (wv * 2 + mf)) * 64 + ln) * 8];
    __builtin_amdgcn_sched_barrier(0);

    auto stageB = [&](int tt, ushort* dst) {
        int tp0 = tt * 64;
        #pragma unroll
        for (int j = 0; j < 4; j++) {
            int unit = j * 512 + t;
            int prow = unit >> 5, c8 = unit & 31;
            int pq = tp0 + prow; if (pq > HW - 1) pq = HW - 1;
            const ushort* g = xb + (size_t)pq * Cc + ((c8 ^ (prow & 7)) << 3);
            ushort* l = dst + (j * 512 + wv * 64) * 8;
            GLL16(g, l);
        }
    };
    stageB(tt0, B0);
    stageB(tt0 + 1, B1);
    __builtin_amdgcn_sched_barrier(0);
    asm volatile("s_waitcnt vmcnt(4)" ::: "memory");
    __builtin_amdgcn_s_barrier();
    __builtin_amdgcn_sched_barrier(0);

    auto compute = [&](int tt, const ushort* Bs) {
        f32x16 acc[2][2];
        #pragma unroll
        for (int mf = 0; mf < 2; mf++)
            #pragma unroll
            for (int pf = 0; pf < 2; pf++)
                #pragma unroll
                for (int r = 0; r < 16; r++) acc[mf][pf][r] = 0.f;
        #pragma unroll
        for (int ks = 0; ks < 16; ks++) {
            int c = ks * 2 + lh;
            #pragma unroll
            for (int pf = 0; pf < 2; pf++) {
                hfrag bf = *(const hfrag*)&Bs[(pf * 32 + l31) * 256 + ((c ^ (l31 & 7)) << 3)];
                acc[0][pf] = MFMA32(A[0][ks], bf, acc[0][pf]);
                acc[1][pf] = MFMA32(A[1][ks], bf, acc[1][pf]);
            }
        }
        const int tp0 = tt * 64;
        #pragma unroll
        for (int mf = 0; mf < 2; mf++) {
            int m0 = wv * 2 + mf;
            const int p_ = m0 >> 3;
            ushort* outb = efp + (size_t)((b * PTS + p_) * HW) * Cc;
            int chb = (m0 * 32) & 255;
            #pragma unroll
            for (int q = 0; q < 4; q++) {
                float4 bv = *(const float4*)&efb[m0 * 32 + q * 8 + 4 * lh];
                #pragma unroll
                for (int pf = 0; pf < 2; pf++) {
                    int px = tp0 + pf * 32 + l31;
                    if (px < HW) {
                        int ch = chb + q * 8 + 4 * lh;
                        ushort4 o = { f2h(acc[mf][pf][q * 4 + 0] + bv.x),
                                      f2h(acc[mf][pf][q * 4 + 1] + bv.y),
                                      f2h(acc[mf][pf][q * 4 + 2] + bv.z),
                                      f2h(acc[mf][pf][q * 4 + 3] + bv.w) };
                        *(ushort4*)&outb[(size_t)px * Cc + ch] = o;
                    }
                }
            }
        }
    };
    compute(tt0, B0);
    asm volatile("s_waitcnt vmcnt(0)" ::: "memory");
    __builtin_amdgcn_s_barrier();
    __builtin_amdgcn_sched_barrier(0);
    compute(tt0 + 1, B1);
}

// ---------------------------------------------------------------------------
// K2: heat = exp(w2.relu(w1@efp + b1) + b2) fused (proven R3)
// ---------------------------------------------------------------------------
__global__ __launch_bounds__(512, 2)
void k_heat(const ushort* __restrict__ efp, const ushort* __restrict__ wb1,
            const float* __restrict__ b1, const float* __restrict__ w2,
            const float* __restrict__ b2, float* __restrict__ heat)
{
    __shared__ ushort B0[64 * 256];
    __shared__ ushort B1[64 * 256];
    __shared__ float red[8][64];
    const int t = threadIdx.x;
    const int wv = t >> 6, ln = t & 63;
    const int l31 = ln & 31, lh = ln >> 5;
    const int zz = blockIdx.y;
    const int b = zz >> 1, p = zz & 1;
    const int tt0 = blockIdx.x * 2;
    const ushort* eb = efp + (size_t)((b * PTS + p) * HW) * Cc;
    const float* b1p = b1 + p * 256;
    const float* w2p = w2 + p * 256;
    const float b2v = b2[p];

    hfrag A[16];
    #pragma unroll
    for (int ks = 0; ks < 16; ks++)
        A[ks] = *(const hfrag*)&wb1[p * 65536 + ((ks * 8 + wv) * 64 + ln) * 8];
    __builtin_amdgcn_sched_barrier(0);

    auto stageB = [&](int tt, ushort* dst) {
        int tp0 = tt * 64;
        #pragma unroll
        for (int j = 0; j < 4; j++) {
            int unit = j * 512 + t;
            int prow = unit >> 5, c8 = unit & 31;
            int pq = tp0 + prow; if (pq > HW - 1) pq = HW - 1;
            const ushort* g = eb + (size_t)pq * Cc + ((c8 ^ (prow & 7)) << 3);
            ushort* l = dst + (j * 512 + wv * 64) * 8;
            GLL16(g, l);
        }
    };
    stageB(tt0, B0);
    stageB(tt0 + 1, B1);
    __builtin_amdgcn_sched_barrier(0);
    asm volatile("s_waitcnt vmcnt(4)" ::: "memory");
    __builtin_amdgcn_s_barrier();
    __builtin_amdgcn_sched_barrier(0);

    auto compute = [&](int tt, const ushort* Bs) {
        f32x16 acc[2];
        #pragma unroll
        for (int pf = 0; pf < 2; pf++)
            #pragma unroll
            for (int r = 0; r < 16; r++) acc[pf][r] = 0.f;
        #pragma unroll
        for (int ks = 0; ks < 16; ks++) {
            int c = ks * 2 + lh;
            #pragma unroll
            for (int pf = 0; pf < 2; pf++) {
                hfrag bf = *(const hfrag*)&Bs[(pf * 32 + l31) * 256 + ((c ^ (l31 & 7)) << 3)];
                acc[pf] = MFMA32(A[ks], bf, acc[pf]);
            }
        }
        float s[2] = {0.f, 0.f};
        #pragma unroll
        for (int q = 0; q < 4; q++) {
            float4 b1v = *(const float4*)&b1p[wv * 32 + q * 8 + 4 * lh];
            float4 w2v = *(const float4*)&w2p[wv * 32 + q * 8 + 4 * lh];
            #pragma unroll
            for (int pf = 0; pf < 2; pf++) {
                float h0 = acc[pf][q * 4 + 0] + b1v.x;
                float h1 = acc[pf][q * 4 + 1] + b1v.y;
                float h2_ = acc[pf][q * 4 + 2] + b1v.z;
                float h3 = acc[pf][q * 4 + 3] + b1v.w;
                s[pf] += w2v.x * (h0 > 0.f ? h0 : 0.f);
                s[pf] += w2v.y * (h1 > 0.f ? h1 : 0.f);
                s[pf] += w2v.z * (h2_ > 0.f ? h2_ : 0.f);
                s[pf] += w2v.w * (h3 > 0.f ? h3 : 0.f);
            }
        }
        s[0] += __shfl_xor(s[0], 32);
        s[1] += __shfl_xor(s[1], 32);
        if (lh == 0) {
            red[wv][l31]      = s[0];
            red[wv][32 + l31] = s[1];
        }
        asm volatile("s_waitcnt lgkmcnt(0)" ::: "memory");
        __builtin_amdgcn_s_barrier();
        if (t < 64) {
            float v = red[0][t] + red[1][t] + red[2][t] + red[3][t] +
                      red[4][t] + red[5][t] + red[6][t] + red[7][t];
            int px = tt * 64 + t;
            if (px < HW) heat[(size_t)(b * PTS + p) * HW + px] = expf(v + b2v);
        }
    };
    compute(tt0, B0);
    asm volatile("s_waitcnt vmcnt(0)" ::: "memory");
    __builtin_amdgcn_s_barrier();
    __builtin_amdgcn_sched_barrier(0);
    compute(tt0 + 1, B1);
}

// ---------------------------------------------------------------------------
// K3: FUSED deformable sampling + merge.  Per block: one 64-px tile, both p.
// Sampled feature rows go to LDS (swizzled [px][512]); merge GEMM runs from
// LDS with merge_w streamed from L2 in 4 chunks.  outs tensor eliminated.
// XCD-contiguous tile decode: each XCD covers a contiguous image strip.
// ---------------------------------------------------------------------------
__global__ __launch_bounds__(512, 2)
void k_sm(const ushort* __restrict__ efp, const float* __restrict__ heat,
          const float* __restrict__ offs, const ushort* __restrict__ wbm,
          const float* __restrict__ mb, ushort* __restrict__ mgb,
          float* __restrict__ part2)
{
    __shared__ ushort Bs[64 * 512];     // 64 KB sampled tile [px][512]
    __shared__ uint2 s_wo[64][20];      // 10 KB weights/offsets
    const int t = threadIdx.x;
    const int wv = t >> 6, ln = t & 63;
    const int l31 = ln & 31, lh = ln >> 5;
    const int bid = blockIdx.x;                 // 0..239
    const int tile = (bid & 7) * 30 + (bid >> 3);
    if (tile >= NTILE) return;
    const int b = blockIdx.y;
    const int m0 = tile * 64;

    // ---- sampling (both p) into Bs ----
    for (int p = 0; p < PTS; p++) {
        const float* heat_bp = heat + (size_t)(b * PTS + p) * HW;
        if (t < 64 * BINS) {
            int j = t / BINS, k = t - (t / BINS) * BINS;
            int hw = m0 + j;
            bool ok = hw < HW;
            int hwc = ok ? hw : HW - 1;
            int hh = hwc / Ww, ww = hwc - hh * Ww;
            int chy = (p * BINS + k) * 2;
            float oy = offs[((size_t)b * (PTS * BINS * 2) + chy)     * HW + hwc];
            float ox = offs[((size_t)b * (PTS * BINS * 2) + chy + 1) * HW + hwc];
            float ysf = (float)hh + oy;
            float xsf = (float)ww + ox;
            float y0 = floorf(ysf), x0 = floorf(xsf);
            #pragma unroll
            for (int dy = 0; dy < 2; dy++)
                #pragma unroll
                for (int dx = 0; dx < 2; dx++) {
                    float yi = y0 + dy, xi = x0 + dx;
                    float wgt = (1.f - fabsf(ysf - yi)) * (1.f - fabsf(xsf - xi));
                    bool valid = ok && (yi >= 0.f) && (yi <= (float)(Hh - 1)) &&
                                 (xi >= 0.f) && (xi <= (float)(Ww - 1));
                    int yc = (int)yi; yc = yc < 0 ? 0 : (yc > Hh - 1 ? Hh - 1 : yc);
                    int xc = (int)xi; xc = xc < 0 ? 0 : (xc > Ww - 1 ? Ww - 1 : xc);
                    int idx = yc * Ww + xc;
                    float wh = valid ? wgt * heat_bp[idx] : 0.f;
                    s_wo[j][k * 4 + dy * 2 + dx] =
                        make_uint2(__float_as_uint(wh), (unsigned)idx << 9);
                }
        }
        asm volatile("s_waitcnt lgkmcnt(0)" ::: "memory");
        __builtin_amdgcn_s_barrier();
        __builtin_amdgcn_sched_barrier(0);
        if (t < 64) {
            float s = 0.f;
            #pragma unroll
            for (int u = 0; u < 20; u++) s += __uint_as_float(s_wo[t][u].x);
            float inv = 1.f / (s + EPS_DIV);
            #pragma unroll
            for (int u = 0; u < 20; u++) {
                float w = __uint_as_float(s_wo[t][u].x) * inv;
                unsigned hw16 = (unsigned)f2h(w);
                s_wo[t][u].x = hw16 | (hw16 << 16);
            }
        }
        asm volatile("s_waitcnt lgkmcnt(0)" ::: "memory");
        __builtin_amdgcn_s_barrier();
        __builtin_amdgcn_sched_barrier(0);

        const int half = lh, c8 = l31;
        const char* efbase = (const char*)(efp + (size_t)((b * PTS + p) * HW) * Cc)
                             + c8 * 16;
        const int g = p * 32 + c8;
        #pragma unroll
        for (int i = 0; i < 8; i += 2) {
            const int j = wv * 8 + i + half;
            h2 a0 = (h2){0, 0}, a1 = (h2){0, 0}, a2 = (h2){0, 0}, a3 = (h2){0, 0};
            #pragma unroll
            for (int u = 0; u < 20; u++) {
                uint2 wo = s_wo[j][u];
                uint4 v = *(const uint4*)(efbase + wo.y);
                h2 wp = __builtin_bit_cast(h2, wo.x);
                a0 += wp * __builtin_bit_cast(h2, v.x);
                a1 += wp * __builtin_bit_cast(h2, v.y);
                a2 += wp * __builtin_bit_cast(h2, v.z);
                a3 += wp * __builtin_bit_cast(h2, v.w);
            }
            uint4 o = { __builtin_bit_cast(unsigned, a0), __builtin_bit_cast(unsigned, a1),
                        __builtin_bit_cast(unsigned, a2), __builtin_bit_cast(unsigned, a3) };
            *(uint4*)&Bs[j * 512 + ((g ^ (j & 7)) << 3)] = o;
        }
        asm volatile("s_waitcnt lgkmcnt(0)" ::: "memory");
        __builtin_amdgcn_s_barrier();
        __builtin_amdgcn_sched_barrier(0);
    }

    // ---- merge GEMM from LDS; A streamed from L2 in 4 chunks ----
    f32x16 acc[2];
    #pragma unroll
    for (int pf = 0; pf < 2; pf++)
        #pragma unroll
        for (int r = 0; r < 16; r++) acc[pf][r] = 0.f;
    #pragma unroll 1
    for (int c4 = 0; c4 < 4; c4++) {
        hfrag A8[8];
        #pragma unroll
        for (int k8 = 0; k8 < 8; k8++)
            A8[k8] = *(const hfrag*)&wbm[(((c4 * 8 + k8) * 8 + wv) * 64 + ln) * 8];
        #pragma unroll
        for (int k8 = 0; k8 < 8; k8++) {
            int c = (c4 * 8 + k8) * 2 + lh;
            #pragma unroll
            for (int pf = 0; pf < 2; pf++) {
                hfrag bf = *(const hfrag*)&Bs[(pf * 32 + l31) * 512 + ((c ^ (l31 & 7)) << 3)];
                acc[pf] = MFMA32(A8[k8], bf, acc[pf]);
            }
        }
    }

    float sg[4] = {0.f, 0.f, 0.f, 0.f};
    float qg[4] = {0.f, 0.f, 0.f, 0.f};
    #pragma unroll
    for (int q = 0; q < 4; q++) {
        float4 bv = *(const float4*)&mb[wv * 32 + q * 8 + 4 * lh];
        #pragma unroll
        for (int pf = 0; pf < 2; pf++) {
            int px = m0 + pf * 32 + l31;
            if (px < HW) {
                #pragma unroll
                for (int r = 0; r < 4; r++) {
                    float bb = r == 0 ? bv.x : (r == 1 ? bv.y : (r == 2 ? bv.z : bv.w));
                    float v = acc[pf][q * 4 + r] + bb;
                    int ch = wv * 32 + q * 8 + 4 * lh + r;
                    mgb[((size_t)b * Cc + ch) * HW + px] = f2h(v);
                    sg[q] += v; qg[q] += v * v;
                }
            }
        }
    }
    #pragma unroll
    for (int q = 0; q < 4; q++) {
        #pragma unroll
        for (int off = 1; off <= 32; off <<= 1) {
            sg[q] += __shfl_xor(sg[q], off);
            qg[q] += __shfl_xor(qg[q], off);
        }
    }
    if (ln == 0) {
        #pragma unroll
        for (int q = 0; q < 4; q++) {
            int g = wv * 4 + q;
            size_t idx = ((size_t)(b * 32 + g) * NTILE + tile) * 2;
            part2[idx + 0] = sg[q];
            part2[idx + 1] = qg[q];
        }
    }
}

// ---------------------------------------------------------------------------
// K5: reduce per-tile GN partials -> mean/istd per (b,group)
// ---------------------------------------------------------------------------
__global__ __launch_bounds__(256)
void k_gnfinal(const float* __restrict__ part2, float* __restrict__ statf)
{
    const int bg = blockIdx.x;
    const int t = threadIdx.x;
    float s = 0.f, q = 0.f;
    if (t < NTILE) {
        s = part2[((size_t)bg * NTILE + t) * 2 + 0];
        q = part2[((size_t)bg * NTILE + t) * 2 + 1];
    }
    #pragma unroll
    for (int off = 1; off <= 32; off <<= 1) {
        s += __shfl_xor(s, off);
        q += __shfl_xor(q, off);
    }
    __shared__ float rs[4], rq[4];
    int wid = t >> 6;
    if ((t & 63) == 0) { rs[wid] = s; rq[wid] = q; }
    __syncthreads();
    if (t == 0) {
        float S = rs[0] + rs[1] + rs[2] + rs[3];
        float Q = rq[0] + rq[1] + rq[2] + rq[3];
        const float n = 8.f * HW;
        float mean = S / n;
        float var  = Q / n - mean * mean;
        statf[bg * 2 + 0] = mean;
        statf[bg * 2 + 1] = rsqrtf(var + GN_EPS);
    }
}

// ---------------------------------------------------------------------------
// K6: apply GN scale/shift + ReLU
// ---------------------------------------------------------------------------
__global__ __launch_bounds__(256)
void k_gnapply(const ushort* __restrict__ mgb, const float* __restrict__ statf,
               const float* __restrict__ gg, const float* __restrict__ gb,
               float* __restrict__ out)
{
    const int i8 = blockIdx.x * 256 + threadIdx.x;
    const int i = i8 * 8;
    const int CHW = Cc * HW;
    const int b = i / CHW;
    const int r = i - b * CHW;
    const int c = r / HW;
    const int g = c >> 3;
    float mean = statf[(b * 32 + g) * 2 + 0];
    float istd = statf[(b * 32 + g) * 2 + 1];
    float sc = istd * gg[c];
    float sh = gb[c] - mean * sc;
    uint4 v = *(const uint4*)(mgb + i);
    float4 o0, o1;
    o0.x = fmaxf(hlo(v.x) * sc + sh, 0.f);
    o0.y = fmaxf(hhi(v.x) * sc + sh, 0.f);
    o0.z = fmaxf(hlo(v.y) * sc + sh, 0.f);
    o0.w = fmaxf(hhi(v.y) * sc + sh, 0.f);
    o1.x = fmaxf(hlo(v.z) * sc + sh, 0.f);
    o1.y = fmaxf(hhi(v.z) * sc + sh, 0.f);
    o1.z = fmaxf(hlo(v.w) * sc + sh, 0.f);
    o1.w = fmaxf(hhi(v.w) * sc + sh, 0.f);
    *(float4*)(out + i)     = o0;
    *(float4*)(out + i + 4) = o1;
}

// ---------------------------------------------------------------------------
extern "C" void kernel_launch(void* const* d_in, const int* in_sizes, int n_in,
                              void* d_out, int out_size, void* d_ws, size_t ws_size,
                              hipStream_t stream)
{
    const float* x    = (const float*)d_in[0];
    const float* offs = (const float*)d_in[1];
    const float* efw  = (const float*)d_in[2];
    const float* efb  = (const float*)d_in[3];
    const float* w1   = (const float*)d_in[4];
    const float* b1   = (const float*)d_in[5];
    const float* w2   = (const float*)d_in[6];
    const float* b2   = (const float*)d_in[7];
    const float* mw   = (const float*)d_in[8];
    const float* mb   = (const float*)d_in[9];
    const float* gg   = (const float*)d_in[10];
    const float* gb   = (const float*)d_in[11];
    float* out = (float*)d_out;

    ushort* wb    = (ushort*)d_ws;
    ushort* wbe   = wb;                          // 131072 (frag order)
    ushort* wb1   = wb + 131072;
    ushort* wbm   = wb + 262144;
    ushort* efp   = wb + 393216;                        // B*P*HW*C fp16
    ushort* outsb = efp + (size_t)Bx * PTS * HW * Cc;   // (unused, reserved)
    ushort* xbt   = outsb + (size_t)Bx * HW * PTS * Cc; // B*HW*C fp16
    ushort* mgb   = xbt + (size_t)Bx * HW * Cc;         // B*C*HW fp16
    float*  heat  = (float*)(mgb + (size_t)Bx * Cc * HW);
    float*  part2 = heat + (size_t)Bx * PTS * HW;       // 64*NTILE*2 floats
    float*  statf = part2 + (size_t)64 * NTILE * 2;     // 128 floats

    dim3 blk(256);
    k_pre    <<<dim3(7792),             blk, 0, stream>>>(efw, w1, mw, wb, x, xbt);
    k_ef     <<<dim3(119, Bx),    dim3(512), 0, stream>>>(xbt, wbe, efb, efp);
    k_heat   <<<dim3(119, 4),     dim3(512), 0, stream>>>(efp, wb1, b1, w2, b2, heat);
    k_sm     <<<dim3(240, Bx),    dim3(512), 0, stream>>>(efp, heat, offs, wbm, mb, mgb, part2);
    k_gnfinal<<<dim3(64),               blk, 0, stream>>>(part2, statf);
    k_gnapply<<<dim3(Bx * Cc * HW / 8 / 256), blk, 0, stream>>>(mgb, statf, gg, gb, out);
}

// Round 5
// 198.199 us; speedup vs baseline: 1.0561x; 1.0001x over previous
//
#include <hip/hip_runtime.h>

#define BINS 5
#define PTS  2
constexpr int Bx = 2, Cc = 256, Hh = 100, Ww = 152;
constexpr int HW = Hh * Ww;          // 15200
constexpr int NTILE = 475;           // 32-px tiles (exact)
constexpr float EPS_DIV = 1e-6f;
constexpr float GN_EPS  = 1e-5f;

typedef __attribute__((ext_vector_type(8)))  _Float16 hfrag;  // 8 fp16
typedef __attribute__((ext_vector_type(2)))  _Float16 h2;
typedef __attribute__((ext_vector_type(16))) float    f32x16; // 32x32 MFMA C/D

__device__ __forceinline__ ushort f2h(float f) {
    return __builtin_bit_cast(ushort, (_Float16)f);
}
__device__ __forceinline__ float hlo(unsigned u) {
    return (float)__builtin_bit_cast(_Float16, (ushort)(u & 0xffffu));
}
__device__ __forceinline__ float hhi(unsigned u) {
    return (float)__builtin_bit_cast(_Float16, (ushort)(u >> 16));
}

#define GLL16(g, l) __builtin_amdgcn_global_load_lds( \
    (const __attribute__((address_space(1))) unsigned*)(g), \
    (__attribute__((address_space(3))) unsigned*)(l), 16, 0, 0)

#define MFMA32(a, b, c) __builtin_amdgcn_mfma_f32_32x32x16_f16(a, b, c, 0, 0, 0)

// ---------------------------------------------------------------------------
// K0: fused preprocessing.  Blocks 0..191: weight convert to fp16 in
// 32x32x16-MFMA fragment order.  Blocks 192..7791: x transpose+convert.
// ---------------------------------------------------------------------------
__global__ __launch_bounds__(256)
void k_pre(const float* __restrict__ efw, const float* __restrict__ w1,
           const float* __restrict__ mw, ushort* __restrict__ wb,
           const float* __restrict__ x, ushort* __restrict__ xbt)
{
    __shared__ float tile[32][33];
    const int bid = blockIdx.x;
    const int t = threadIdx.x;
    if (bid < 192) {
        int gid = bid * 256 + t;
        int i = gid * 8;
        int arr = i >> 17, off = i & 131071;
        const float* src = arr == 0 ? efw : (arr == 1 ? w1 : mw);
        float4 v0 = *(const float4*)(src + off);
        float4 v1 = *(const float4*)(src + off + 4);
        int outaddr;
        if (arr == 0) {                // ef_w: M=512, K=256
            int m = off >> 8, k = off & 255;
            outaddr = (((k >> 4) * 16 + (m >> 5)) * 64 + (m & 31) + 32 * ((k >> 3) & 1)) * 8;
        } else if (arr == 1) {         // hm1_w: per p, M=256, K=256
            int p = off >> 16, r = off & 65535;
            int m = r >> 8, k = r & 255;
            outaddr = p * 65536 +
                      (((k >> 4) * 8 + (m >> 5)) * 64 + (m & 31) + 32 * ((k >> 3) & 1)) * 8;
        } else {                       // merge_w: M=256, K=512
            int m = off >> 9, k = off & 511;
            outaddr = (((k >> 4) * 8 + (m >> 5)) * 64 + (m & 31) + 32 * ((k >> 3) & 1)) * 8;
        }
        ushort o[8] = { f2h(v0.x), f2h(v0.y), f2h(v0.z), f2h(v0.w),
                        f2h(v1.x), f2h(v1.y), f2h(v1.z), f2h(v1.w) };
        *(uint4*)(wb + arr * 131072 + outaddr) = *(uint4*)o;
    } else {
        int r = bid - 192;             // 0..7599
        const int b = r / 3800; r -= b * 3800;
        const int c0 = (r / 475) * 32;
        const int hw0 = (r % 475) * 32;
        const float* xb = x + ((size_t)b * Cc + c0) * HW + hw0;
        const int tx = t & 31, ty = t >> 5;
        #pragma unroll
        for (int rr = 0; rr < 4; rr++) {
            int c = ty + rr * 8;
            tile[c][tx] = xb[(size_t)c * HW + tx];
        }
        __syncthreads();
        const int hwl = t >> 3, c4 = (t & 7) * 4;
        ushort4 o = { f2h(tile[c4 + 0][hwl]), f2h(tile[c4 + 1][hwl]),
                      f2h(tile[c4 + 2][hwl]), f2h(tile[c4 + 3][hwl]) };
        *(ushort4*)&xbt[((size_t)b * HW + hw0 + hwl) * Cc + c0 + c4] = o;
    }
}

// ---------------------------------------------------------------------------
// K1: efp = ef_w @ x + ef_b.  A (512x256) in registers, LDS = B only
// (2 x 32KB dbuf), 32x32x16 MFMA, counted vmcnt.  (proven R3)
// ---------------------------------------------------------------------------
__global__ __launch_bounds__(512, 2)
void k_ef(const ushort* __restrict__ xbt, const ushort* __restrict__ wbe,
          const float* __restrict__ efb, ushort* __restrict__ efp)
{
    __shared__ ushort B0[64 * 256];
    __shared__ ushort B1[64 * 256];
    const int t = threadIdx.x;
    const int wv = t >> 6, ln = t & 63;
    const int l31 = ln & 31, lh = ln >> 5;
    const int b = blockIdx.y;
    const int tt0 = blockIdx.x * 2;
    const ushort* xb = xbt + (size_t)b * HW * Cc;

    hfrag A[2][16];
    #pragma unroll
    for (int mf = 0; mf < 2; mf++)
        #pragma unroll
        for (int ks = 0; ks < 16; ks++)
            A[mf][ks] = *(const hfrag*)&wbe[((ks * 16 + (wv * 2 + mf)) * 64 + ln) * 8];
    __builtin_amdgcn_sched_barrier(0);

    auto stageB = [&](int tt, ushort* dst) {
        int tp0 = tt * 64;
        #pragma unroll
        for (int j = 0; j < 4; j++) {
            int unit = j * 512 + t;
            int prow = unit >> 5, c8 = unit & 31;
            int pq = tp0 + prow; if (pq > HW - 1) pq = HW - 1;
            const ushort* g = xb + (size_t)pq * Cc + ((c8 ^ (prow & 7)) << 3);
            ushort* l = dst + (j * 512 + wv * 64) * 8;
            GLL16(g, l);
        }
    };
    stageB(tt0, B0);
    stageB(tt0 + 1, B1);
    __builtin_amdgcn_sched_barrier(0);
    asm volatile("s_waitcnt vmcnt(4)" ::: "memory");
    __builtin_amdgcn_s_barrier();
    __builtin_amdgcn_sched_barrier(0);

    auto compute = [&](int tt, const ushort* Bs) {
        f32x16 acc[2][2];
        #pragma unroll
        for (int mf = 0; mf < 2; mf++)
            #pragma unroll
            for (int pf = 0; pf < 2; pf++)
                #pragma unroll
                for (int r = 0; r < 16; r++) acc[mf][pf][r] = 0.f;
        #pragma unroll
        for (int ks = 0; ks < 16; ks++) {
            int c = ks * 2 + lh;
            #pragma unroll
            for (int pf = 0; pf < 2; pf++) {
                hfrag bf = *(const hfrag*)&Bs[(pf * 32 + l31) * 256 + ((c ^ (l31 & 7)) << 3)];
                acc[0][pf] = MFMA32(A[0][ks], bf, acc[0][pf]);
                acc[1][pf] = MFMA32(A[1][ks], bf, acc[1][pf]);
            }
        }
        const int tp0 = tt * 64;
        #pragma unroll
        for (int mf = 0; mf < 2; mf++) {
            int m0 = wv * 2 + mf;
            const int p_ = m0 >> 3;
            ushort* outb = efp + (size_t)((b * PTS + p_) * HW) * Cc;
            int chb = (m0 * 32) & 255;
            #pragma unroll
            for (int q = 0; q < 4; q++) {
                float4 bv = *(const float4*)&efb[m0 * 32 + q * 8 + 4 * lh];
                #pragma unroll
                for (int pf = 0; pf < 2; pf++) {
                    int px = tp0 + pf * 32 + l31;
                    if (px < HW) {
                        int ch = chb + q * 8 + 4 * lh;
                        ushort4 o = { f2h(acc[mf][pf][q * 4 + 0] + bv.x),
                                      f2h(acc[mf][pf][q * 4 + 1] + bv.y),
                                      f2h(acc[mf][pf][q * 4 + 2] + bv.z),
                                      f2h(acc[mf][pf][q * 4 + 3] + bv.w) };
                        *(ushort4*)&outb[(size_t)px * Cc + ch] = o;
                    }
                }
            }
        }
    };
    compute(tt0, B0);
    asm volatile("s_waitcnt vmcnt(0)" ::: "memory");
    __builtin_amdgcn_s_barrier();
    __builtin_amdgcn_sched_barrier(0);
    compute(tt0 + 1, B1);
}

// ---------------------------------------------------------------------------
// K2: heat = exp(w2.relu(w1@efp + b1) + b2) fused (proven R3)
// ---------------------------------------------------------------------------
__global__ __launch_bounds__(512, 2)
void k_heat(const ushort* __restrict__ efp, const ushort* __restrict__ wb1,
            const float* __restrict__ b1, const float* __restrict__ w2,
            const float* __restrict__ b2, float* __restrict__ heat)
{
    __shared__ ushort B0[64 * 256];
    __shared__ ushort B1[64 * 256];
    __shared__ float red[8][64];
    const int t = threadIdx.x;
    const int wv = t >> 6, ln = t & 63;
    const int l31 = ln & 31, lh = ln >> 5;
    const int zz = blockIdx.y;
    const int b = zz >> 1, p = zz & 1;
    const int tt0 = blockIdx.x * 2;
    const ushort* eb = efp + (size_t)((b * PTS + p) * HW) * Cc;
    const float* b1p = b1 + p * 256;
    const float* w2p = w2 + p * 256;
    const float b2v = b2[p];

    hfrag A[16];
    #pragma unroll
    for (int ks = 0; ks < 16; ks++)
        A[ks] = *(const hfrag*)&wb1[p * 65536 + ((ks * 8 + wv) * 64 + ln) * 8];
    __builtin_amdgcn_sched_barrier(0);

    auto stageB = [&](int tt, ushort* dst) {
        int tp0 = tt * 64;
        #pragma unroll
        for (int j = 0; j < 4; j++) {
            int unit = j * 512 + t;
            int prow = unit >> 5, c8 = unit & 31;
            int pq = tp0 + prow; if (pq > HW - 1) pq = HW - 1;
            const ushort* g = eb + (size_t)pq * Cc + ((c8 ^ (prow & 7)) << 3);
            ushort* l = dst + (j * 512 + wv * 64) * 8;
            GLL16(g, l);
        }
    };
    stageB(tt0, B0);
    stageB(tt0 + 1, B1);
    __builtin_amdgcn_sched_barrier(0);
    asm volatile("s_waitcnt vmcnt(4)" ::: "memory");
    __builtin_amdgcn_s_barrier();
    __builtin_amdgcn_sched_barrier(0);

    auto compute = [&](int tt, const ushort* Bs) {
        f32x16 acc[2];
        #pragma unroll
        for (int pf = 0; pf < 2; pf++)
            #pragma unroll
            for (int r = 0; r < 16; r++) acc[pf][r] = 0.f;
        #pragma unroll
        for (int ks = 0; ks < 16; ks++) {
            int c = ks * 2 + lh;
            #pragma unroll
            for (int pf = 0; pf < 2; pf++) {
                hfrag bf = *(const hfrag*)&Bs[(pf * 32 + l31) * 256 + ((c ^ (l31 & 7)) << 3)];
                acc[pf] = MFMA32(A[ks], bf, acc[pf]);
            }
        }
        float s[2] = {0.f, 0.f};
        #pragma unroll
        for (int q = 0; q < 4; q++) {
            float4 b1v = *(const float4*)&b1p[wv * 32 + q * 8 + 4 * lh];
            float4 w2v = *(const float4*)&w2p[wv * 32 + q * 8 + 4 * lh];
            #pragma unroll
            for (int pf = 0; pf < 2; pf++) {
                float h0 = acc[pf][q * 4 + 0] + b1v.x;
                float h1 = acc[pf][q * 4 + 1] + b1v.y;
                float h2_ = acc[pf][q * 4 + 2] + b1v.z;
                float h3 = acc[pf][q * 4 + 3] + b1v.w;
                s[pf] += w2v.x * (h0 > 0.f ? h0 : 0.f);
                s[pf] += w2v.y * (h1 > 0.f ? h1 : 0.f);
                s[pf] += w2v.z * (h2_ > 0.f ? h2_ : 0.f);
                s[pf] += w2v.w * (h3 > 0.f ? h3 : 0.f);
            }
        }
        s[0] += __shfl_xor(s[0], 32);
        s[1] += __shfl_xor(s[1], 32);
        if (lh == 0) {
            red[wv][l31]      = s[0];
            red[wv][32 + l31] = s[1];
        }
        asm volatile("s_waitcnt lgkmcnt(0)" ::: "memory");
        __builtin_amdgcn_s_barrier();
        if (t < 64) {
            float v = red[0][t] + red[1][t] + red[2][t] + red[3][t] +
                      red[4][t] + red[5][t] + red[6][t] + red[7][t];
            int px = tt * 64 + t;
            if (px < HW) heat[(size_t)(b * PTS + p) * HW + px] = expf(v + b2v);
        }
    };
    compute(tt0, B0);
    asm volatile("s_waitcnt vmcnt(0)" ::: "memory");
    __builtin_amdgcn_s_barrier();
    __builtin_amdgcn_sched_barrier(0);
    compute(tt0 + 1, B1);
}

// ---------------------------------------------------------------------------
// K3: FUSED sampling + merge, 32-px tiles for occupancy.  Waves 0-3 gather
// p=0, waves 4-7 gather p=1 concurrently into disjoint column halves of the
// LDS tile; then merge GEMM (M=256, N=32, K=512) from LDS.  3 barriers.
// ---------------------------------------------------------------------------
__global__ __launch_bounds__(512, 2)
void k_sm(const ushort* __restrict__ efp, const float* __restrict__ heat,
          const float* __restrict__ offs, const ushort* __restrict__ wbm,
          const float* __restrict__ mb, ushort* __restrict__ mgb,
          float* __restrict__ part2)
{
    __shared__ ushort Bs[32 * 512];     // 32 KB sampled tile [px][512]
    __shared__ uint2 s_wo[2][32][20];   // 10 KB weights/offsets
    const int t = threadIdx.x;
    const int wv = t >> 6, ln = t & 63;
    const int l31 = ln & 31, lh = ln >> 5;
    // bijective XCD decode for 475 tiles: q=59, r=3
    const int bid = blockIdx.x;
    const int xcd = bid & 7, ii = bid >> 3;
    const int tile = (xcd < 3 ? xcd * 60 : 180 + (xcd - 3) * 59) + ii;
    const int b = blockIdx.y;
    const int m0 = tile * 32;

    // ---- phase 1: bilinear weights for both p (320 threads) ----
    if (t < 32 * BINS * PTS) {
        int p = t / 160, r = t - p * 160;
        int j = r / BINS, k = r - (r / BINS) * BINS;
        int hw = m0 + j;
        int hh = hw / Ww, ww = hw - hh * Ww;
        const float* heat_bp = heat + (size_t)(b * PTS + p) * HW;
        int chy = (p * BINS + k) * 2;
        float oy = offs[((size_t)b * (PTS * BINS * 2) + chy)     * HW + hw];
        float ox = offs[((size_t)b * (PTS * BINS * 2) + chy + 1) * HW + hw];
        float ysf = (float)hh + oy;
        float xsf = (float)ww + ox;
        float y0 = floorf(ysf), x0 = floorf(xsf);
        #pragma unroll
        for (int dy = 0; dy < 2; dy++)
            #pragma unroll
            for (int dx = 0; dx < 2; dx++) {
                float yi = y0 + dy, xi = x0 + dx;
                float wgt = (1.f - fabsf(ysf - yi)) * (1.f - fabsf(xsf - xi));
                bool valid = (yi >= 0.f) && (yi <= (float)(Hh - 1)) &&
                             (xi >= 0.f) && (xi <= (float)(Ww - 1));
                int yc = (int)yi; yc = yc < 0 ? 0 : (yc > Hh - 1 ? Hh - 1 : yc);
                int xc = (int)xi; xc = xc < 0 ? 0 : (xc > Ww - 1 ? Ww - 1 : xc);
                int idx = yc * Ww + xc;
                float wh = valid ? wgt * heat_bp[idx] : 0.f;
                s_wo[p][j][k * 4 + dy * 2 + dx] =
                    make_uint2(__float_as_uint(wh), (unsigned)idx << 9);
            }
    }
    __syncthreads();
    // ---- phase 2: normalize (64 threads: p = t>>5, px = t&31) ----
    if (t < 64) {
        int p = t >> 5, px = t & 31;
        float s = 0.f;
        #pragma unroll
        for (int u = 0; u < 20; u++) s += __uint_as_float(s_wo[p][px][u].x);
        float inv = 1.f / (s + EPS_DIV);
        #pragma unroll
        for (int u = 0; u < 20; u++) {
            float w = __uint_as_float(s_wo[p][px][u].x) * inv;
            unsigned hw16 = (unsigned)f2h(w);
            s_wo[p][px][u].x = hw16 | (hw16 << 16);
        }
    }
    __syncthreads();

    // ---- phase 3: gather.  wave wv: p = wv>>2, pixels (wv&3)*8 .. +7 ----
    {
        const int p = wv >> 2;
        const int jb = (wv & 3) * 8;
        const int g = p * 32 + l31;          // column unit (16B) in [0,64)
        const char* efbase = (const char*)(efp + (size_t)((b * PTS + p) * HW) * Cc)
                             + l31 * 16;
        #pragma unroll
        for (int i2 = 0; i2 < 8; i2 += 2) {
            const int j = jb + i2 + lh;
            h2 a0 = (h2){0, 0}, a1 = (h2){0, 0}, a2 = (h2){0, 0}, a3 = (h2){0, 0};
            #pragma unroll
            for (int u = 0; u < 20; u++) {
                uint2 wo = s_wo[p][j][u];
                uint4 v = *(const uint4*)(efbase + wo.y);
                h2 wp = __builtin_bit_cast(h2, wo.x);
                a0 += wp * __builtin_bit_cast(h2, v.x);
                a1 += wp * __builtin_bit_cast(h2, v.y);
                a2 += wp * __builtin_bit_cast(h2, v.z);
                a3 += wp * __builtin_bit_cast(h2, v.w);
            }
            uint4 o = { __builtin_bit_cast(unsigned, a0), __builtin_bit_cast(unsigned, a1),
                        __builtin_bit_cast(unsigned, a2), __builtin_bit_cast(unsigned, a3) };
            *(uint4*)&Bs[j * 512 + ((g ^ j) << 3)] = o;
        }
    }
    __syncthreads();

    // ---- phase 4: merge GEMM (M=256, N=32, K=512); A streamed from L2 ----
    f32x16 acc;
    #pragma unroll
    for (int r = 0; r < 16; r++) acc[r] = 0.f;
    #pragma unroll 1
    for (int c4 = 0; c4 < 4; c4++) {
        hfrag A8[8];
        #pragma unroll
        for (int k8 = 0; k8 < 8; k8++)
            A8[k8] = *(const hfrag*)&wbm[(((c4 * 8 + k8) * 8 + wv) * 64 + ln) * 8];
        #pragma unroll
        for (int k8 = 0; k8 < 8; k8++) {
            int c = (c4 * 8 + k8) * 2 + lh;
            hfrag bf = *(const hfrag*)&Bs[l31 * 512 + ((c ^ l31) << 3)];
            acc = MFMA32(A8[k8], bf, acc);
        }
    }

    const int px = m0 + l31;                 // always < HW (475*32 = 15200)
    float sg[4] = {0.f, 0.f, 0.f, 0.f};
    float qg[4] = {0.f, 0.f, 0.f, 0.f};
    #pragma unroll
    for (int q = 0; q < 4; q++) {
        float4 bv = *(const float4*)&mb[wv * 32 + q * 8 + 4 * lh];
        #pragma unroll
        for (int r = 0; r < 4; r++) {
            float bb = r == 0 ? bv.x : (r == 1 ? bv.y : (r == 2 ? bv.z : bv.w));
            float v = acc[q * 4 + r] + bb;
            int ch = wv * 32 + q * 8 + 4 * lh + r;
            mgb[((size_t)b * Cc + ch) * HW + px] = f2h(v);
            sg[q] += v; qg[q] += v * v;
        }
    }
    #pragma unroll
    for (int q = 0; q < 4; q++) {
        #pragma unroll
        for (int off = 1; off <= 32; off <<= 1) {
            sg[q] += __shfl_xor(sg[q], off);
            qg[q] += __shfl_xor(qg[q], off);
        }
    }
    if (ln == 0) {
        #pragma unroll
        for (int q = 0; q < 4; q++) {
            int g = wv * 4 + q;
            size_t idx = ((size_t)(b * 32 + g) * NTILE + tile) * 2;
            part2[idx + 0] = sg[q];
            part2[idx + 1] = qg[q];
        }
    }
}

// ---------------------------------------------------------------------------
// K5: reduce per-tile GN partials -> mean/istd per (b,group)
// ---------------------------------------------------------------------------
__global__ __launch_bounds__(256)
void k_gnfinal(const float* __restrict__ part2, float* __restrict__ statf)
{
    const int bg = blockIdx.x;
    const int t = threadIdx.x;
    float s = 0.f, q = 0.f;
    for (int u = t; u < NTILE; u += 256) {
        s += part2[((size_t)bg * NTILE + u) * 2 + 0];
        q += part2[((size_t)bg * NTILE + u) * 2 + 1];
    }
    #pragma unroll
    for (int off = 1; off <= 32; off <<= 1) {
        s += __shfl_xor(s, off);
        q += __shfl_xor(q, off);
    }
    __shared__ float rs[4], rq[4];
    int wid = t >> 6;
    if ((t & 63) == 0) { rs[wid] = s; rq[wid] = q; }
    __syncthreads();
    if (t == 0) {
        float S = rs[0] + rs[1] + rs[2] + rs[3];
        float Q = rq[0] + rq[1] + rq[2] + rq[3];
        const float n = 8.f * HW;
        float mean = S / n;
        float var  = Q / n - mean * mean;
        statf[bg * 2 + 0] = mean;
        statf[bg * 2 + 1] = rsqrtf(var + GN_EPS);
    }
}

// ---------------------------------------------------------------------------
// K6: apply GN scale/shift + ReLU
// ---------------------------------------------------------------------------
__global__ __launch_bounds__(256)
void k_gnapply(const ushort* __restrict__ mgb, const float* __restrict__ statf,
               const float* __restrict__ gg, const float* __restrict__ gb,
               float* __restrict__ out)
{
    const int i8 = blockIdx.x * 256 + threadIdx.x;
    const int i = i8 * 8;
    const int CHW = Cc * HW;
    const int b = i / CHW;
    const int r = i - b * CHW;
    const int c = r / HW;
    const int g = c >> 3;
    float mean = statf[(b * 32 + g) * 2 + 0];
    float istd = statf[(b * 32 + g) * 2 + 1];
    float sc = istd * gg[c];
    float sh = gb[c] - mean * sc;
    uint4 v = *(const uint4*)(mgb + i);
    float4 o0, o1;
    o0.x = fmaxf(hlo(v.x) * sc + sh, 0.f);
    o0.y = fmaxf(hhi(v.x) * sc + sh, 0.f);
    o0.z = fmaxf(hlo(v.y) * sc + sh, 0.f);
    o0.w = fmaxf(hhi(v.y) * sc + sh, 0.f);
    o1.x = fmaxf(hlo(v.z) * sc + sh, 0.f);
    o1.y = fmaxf(hhi(v.z) * sc + sh, 0.f);
    o1.z = fmaxf(hlo(v.w) * sc + sh, 0.f);
    o1.w = fmaxf(hhi(v.w) * sc + sh, 0.f);
    *(float4*)(out + i)     = o0;
    *(float4*)(out + i + 4) = o1;
}

// ---------------------------------------------------------------------------
extern "C" void kernel_launch(void* const* d_in, const int* in_sizes, int n_in,
                              void* d_out, int out_size, void* d_ws, size_t ws_size,
                              hipStream_t stream)
{
    const float* x    = (const float*)d_in[0];
    const float* offs = (const float*)d_in[1];
    const float* efw  = (const float*)d_in[2];
    const float* efb  = (const float*)d_in[3];
    const float* w1   = (const float*)d_in[4];
    const float* b1   = (const float*)d_in[5];
    const float* w2   = (const float*)d_in[6];
    const float* b2   = (const float*)d_in[7];
    const float* mw   = (const float*)d_in[8];
    const float* mb   = (const float*)d_in[9];
    const float* gg   = (const float*)d_in[10];
    const float* gb   = (const float*)d_in[11];
    float* out = (float*)d_out;

    ushort* wb    = (ushort*)d_ws;
    ushort* wbe   = wb;                          // 131072 (frag order)
    ushort* wb1   = wb + 131072;
    ushort* wbm   = wb + 262144;
    ushort* efp   = wb + 393216;                        // B*P*HW*C fp16
    ushort* xbt   = efp + (size_t)Bx * PTS * HW * Cc;   // B*HW*C fp16
    ushort* mgb   = xbt + (size_t)Bx * HW * Cc;         // B*C*HW fp16
    float*  heat  = (float*)(mgb + (size_t)Bx * Cc * HW);
    float*  part2 = heat + (size_t)Bx * PTS * HW;       // 64*NTILE*2 floats
    float*  statf = part2 + (size_t)64 * NTILE * 2;     // 128 floats

    dim3 blk(256);
    k_pre    <<<dim3(7792),             blk, 0, stream>>>(efw, w1, mw, wb, x, xbt);
    k_ef     <<<dim3(119, Bx),    dim3(512), 0, stream>>>(xbt, wbe, efb, efp);
    k_heat   <<<dim3(119, 4),     dim3(512), 0, stream>>>(efp, wb1, b1, w2, b2, heat);
    k_sm     <<<dim3(475, Bx),    dim3(512), 0, stream>>>(efp, heat, offs, wbm, mb, mgb, part2);
    k_gnfinal<<<dim3(64),               blk, 0, stream>>>(part2, statf);
    k_gnapply<<<dim3(Bx * Cc * HW / 8 / 256), blk, 0, stream>>>(mgb, statf, gg, gb, out);
}

// Round 6
// 197.110 us; speedup vs baseline: 1.0619x; 1.0055x over previous
//
#include <hip/hip_runtime.h>

#define BINS 5
#define PTS  2
constexpr int Bx = 2, Cc = 256, Hh = 100, Ww = 152;
constexpr int HW = Hh * Ww;          // 15200
constexpr int NTILE = 475;           // 32-px tiles (exact)
constexpr float EPS_DIV = 1e-6f;
constexpr float GN_EPS  = 1e-5f;

typedef __attribute__((ext_vector_type(8)))  _Float16 hfrag;  // 8 fp16
typedef __attribute__((ext_vector_type(2)))  _Float16 h2;
typedef __attribute__((ext_vector_type(16))) float    f32x16; // 32x32 MFMA C/D

__device__ __forceinline__ ushort f2h(float f) {
    return __builtin_bit_cast(ushort, (_Float16)f);
}
__device__ __forceinline__ float hlo(unsigned u) {
    return (float)__builtin_bit_cast(_Float16, (ushort)(u & 0xffffu));
}
__device__ __forceinline__ float hhi(unsigned u) {
    return (float)__builtin_bit_cast(_Float16, (ushort)(u >> 16));
}

#define GLL16(g, l) __builtin_amdgcn_global_load_lds( \
    (const __attribute__((address_space(1))) unsigned*)(g), \
    (__attribute__((address_space(3))) unsigned*)(l), 16, 0, 0)

#define MFMA32(a, b, c) __builtin_amdgcn_mfma_f32_32x32x16_f16(a, b, c, 0, 0, 0)

// ---------------------------------------------------------------------------
// K0: fused preprocessing.  Blocks 0..191: weight convert to fp16 in
// 32x32x16-MFMA fragment order.  Blocks 192..7791: x transpose+convert.
// ---------------------------------------------------------------------------
__global__ __launch_bounds__(256)
void k_pre(const float* __restrict__ efw, const float* __restrict__ w1,
           const float* __restrict__ mw, ushort* __restrict__ wb,
           const float* __restrict__ x, ushort* __restrict__ xbt)
{
    __shared__ float tile[32][33];
    const int bid = blockIdx.x;
    const int t = threadIdx.x;
    if (bid < 192) {
        int gid = bid * 256 + t;
        int i = gid * 8;
        int arr = i >> 17, off = i & 131071;
        const float* src = arr == 0 ? efw : (arr == 1 ? w1 : mw);
        float4 v0 = *(const float4*)(src + off);
        float4 v1 = *(const float4*)(src + off + 4);
        int outaddr;
        if (arr == 0) {                // ef_w: M=512, K=256
            int m = off >> 8, k = off & 255;
            outaddr = (((k >> 4) * 16 + (m >> 5)) * 64 + (m & 31) + 32 * ((k >> 3) & 1)) * 8;
        } else if (arr == 1) {         // hm1_w: per p, M=256, K=256
            int p = off >> 16, r = off & 65535;
            int m = r >> 8, k = r & 255;
            outaddr = p * 65536 +
                      (((k >> 4) * 8 + (m >> 5)) * 64 + (m & 31) + 32 * ((k >> 3) & 1)) * 8;
        } else {                       // merge_w: M=256, K=512
            int m = off >> 9, k = off & 511;
            outaddr = (((k >> 4) * 8 + (m >> 5)) * 64 + (m & 31) + 32 * ((k >> 3) & 1)) * 8;
        }
        ushort o[8] = { f2h(v0.x), f2h(v0.y), f2h(v0.z), f2h(v0.w),
                        f2h(v1.x), f2h(v1.y), f2h(v1.z), f2h(v1.w) };
        *(uint4*)(wb + arr * 131072 + outaddr) = *(uint4*)o;
    } else {
        int r = bid - 192;             // 0..7599
        const int b = r / 3800; r -= b * 3800;
        const int c0 = (r / 475) * 32;
        const int hw0 = (r % 475) * 32;
        const float* xb = x + ((size_t)b * Cc + c0) * HW + hw0;
        const int tx = t & 31, ty = t >> 5;
        #pragma unroll
        for (int rr = 0; rr < 4; rr++) {
            int c = ty + rr * 8;
            tile[c][tx] = xb[(size_t)c * HW + tx];
        }
        __syncthreads();
        const int hwl = t >> 3, c4 = (t & 7) * 4;
        ushort4 o = { f2h(tile[c4 + 0][hwl]), f2h(tile[c4 + 1][hwl]),
                      f2h(tile[c4 + 2][hwl]), f2h(tile[c4 + 3][hwl]) };
        *(ushort4*)&xbt[((size_t)b * HW + hw0 + hwl) * Cc + c0 + c4] = o;
    }
}

// ---------------------------------------------------------------------------
// K1: efp = ef_w @ x + ef_b.  A (512x256) in registers, LDS = B only
// (2 x 32KB dbuf), 32x32x16 MFMA, counted vmcnt.  (proven R3)
// ---------------------------------------------------------------------------
__global__ __launch_bounds__(512, 2)
void k_ef(const ushort* __restrict__ xbt, const ushort* __restrict__ wbe,
          const float* __restrict__ efb, ushort* __restrict__ efp)
{
    __shared__ ushort B0[64 * 256];
    __shared__ ushort B1[64 * 256];
    const int t = threadIdx.x;
    const int wv = t >> 6, ln = t & 63;
    const int l31 = ln & 31, lh = ln >> 5;
    const int b = blockIdx.y;
    const int tt0 = blockIdx.x * 2;
    const ushort* xb = xbt + (size_t)b * HW * Cc;

    hfrag A[2][16];
    #pragma unroll
    for (int mf = 0; mf < 2; mf++)
        #pragma unroll
        for (int ks = 0; ks < 16; ks++)
            A[mf][ks] = *(const hfrag*)&wbe[((ks * 16 + (wv * 2 + mf)) * 64 + ln) * 8];
    __builtin_amdgcn_sched_barrier(0);

    auto stageB = [&](int tt, ushort* dst) {
        int tp0 = tt * 64;
        #pragma unroll
        for (int j = 0; j < 4; j++) {
            int unit = j * 512 + t;
            int prow = unit >> 5, c8 = unit & 31;
            int pq = tp0 + prow; if (pq > HW - 1) pq = HW - 1;
            const ushort* g = xb + (size_t)pq * Cc + ((c8 ^ (prow & 7)) << 3);
            ushort* l = dst + (j * 512 + wv * 64) * 8;
            GLL16(g, l);
        }
    };
    stageB(tt0, B0);
    stageB(tt0 + 1, B1);
    __builtin_amdgcn_sched_barrier(0);
    asm volatile("s_waitcnt vmcnt(4)" ::: "memory");
    __builtin_amdgcn_s_barrier();
    __builtin_amdgcn_sched_barrier(0);

    auto compute = [&](int tt, const ushort* Bs) {
        f32x16 acc[2][2];
        #pragma unroll
        for (int mf = 0; mf < 2; mf++)
            #pragma unroll
            for (int pf = 0; pf < 2; pf++)
                #pragma unroll
                for (int r = 0; r < 16; r++) acc[mf][pf][r] = 0.f;
        #pragma unroll
        for (int ks = 0; ks < 16; ks++) {
            int c = ks * 2 + lh;
            #pragma unroll
            for (int pf = 0; pf < 2; pf++) {
                hfrag bf = *(const hfrag*)&Bs[(pf * 32 + l31) * 256 + ((c ^ (l31 & 7)) << 3)];
                acc[0][pf] = MFMA32(A[0][ks], bf, acc[0][pf]);
                acc[1][pf] = MFMA32(A[1][ks], bf, acc[1][pf]);
            }
        }
        const int tp0 = tt * 64;
        #pragma unroll
        for (int mf = 0; mf < 2; mf++) {
            int m0 = wv * 2 + mf;
            const int p_ = m0 >> 3;
            ushort* outb = efp + (size_t)((b * PTS + p_) * HW) * Cc;
            int chb = (m0 * 32) & 255;
            #pragma unroll
            for (int q = 0; q < 4; q++) {
                float4 bv = *(const float4*)&efb[m0 * 32 + q * 8 + 4 * lh];
                #pragma unroll
                for (int pf = 0; pf < 2; pf++) {
                    int px = tp0 + pf * 32 + l31;
                    if (px < HW) {
                        int ch = chb + q * 8 + 4 * lh;
                        ushort4 o = { f2h(acc[mf][pf][q * 4 + 0] + bv.x),
                                      f2h(acc[mf][pf][q * 4 + 1] + bv.y),
                                      f2h(acc[mf][pf][q * 4 + 2] + bv.z),
                                      f2h(acc[mf][pf][q * 4 + 3] + bv.w) };
                        *(ushort4*)&outb[(size_t)px * Cc + ch] = o;
                    }
                }
            }
        }
    };
    compute(tt0, B0);
    asm volatile("s_waitcnt vmcnt(0)" ::: "memory");
    __builtin_amdgcn_s_barrier();
    __builtin_amdgcn_sched_barrier(0);
    compute(tt0 + 1, B1);
}

// ---------------------------------------------------------------------------
// K2: heat = exp(w2.relu(w1@efp + b1) + b2) fused (proven R3)
// ---------------------------------------------------------------------------
__global__ __launch_bounds__(512, 2)
void k_heat(const ushort* __restrict__ efp, const ushort* __restrict__ wb1,
            const float* __restrict__ b1, const float* __restrict__ w2,
            const float* __restrict__ b2, float* __restrict__ heat)
{
    __shared__ ushort B0[64 * 256];
    __shared__ ushort B1[64 * 256];
    __shared__ float red[8][64];
    const int t = threadIdx.x;
    const int wv = t >> 6, ln = t & 63;
    const int l31 = ln & 31, lh = ln >> 5;
    const int zz = blockIdx.y;
    const int b = zz >> 1, p = zz & 1;
    const int tt0 = blockIdx.x * 2;
    const ushort* eb = efp + (size_t)((b * PTS + p) * HW) * Cc;
    const float* b1p = b1 + p * 256;
    const float* w2p = w2 + p * 256;
    const float b2v = b2[p];

    hfrag A[16];
    #pragma unroll
    for (int ks = 0; ks < 16; ks++)
        A[ks] = *(const hfrag*)&wb1[p * 65536 + ((ks * 8 + wv) * 64 + ln) * 8];
    __builtin_amdgcn_sched_barrier(0);

    auto stageB = [&](int tt, ushort* dst) {
        int tp0 = tt * 64;
        #pragma unroll
        for (int j = 0; j < 4; j++) {
            int unit = j * 512 + t;
            int prow = unit >> 5, c8 = unit & 31;
            int pq = tp0 + prow; if (pq > HW - 1) pq = HW - 1;
            const ushort* g = eb + (size_t)pq * Cc + ((c8 ^ (prow & 7)) << 3);
            ushort* l = dst + (j * 512 + wv * 64) * 8;
            GLL16(g, l);
        }
    };
    stageB(tt0, B0);
    stageB(tt0 + 1, B1);
    __builtin_amdgcn_sched_barrier(0);
    asm volatile("s_waitcnt vmcnt(4)" ::: "memory");
    __builtin_amdgcn_s_barrier();
    __builtin_amdgcn_sched_barrier(0);

    auto compute = [&](int tt, const ushort* Bs) {
        f32x16 acc[2];
        #pragma unroll
        for (int pf = 0; pf < 2; pf++)
            #pragma unroll
            for (int r = 0; r < 16; r++) acc[pf][r] = 0.f;
        #pragma unroll
        for (int ks = 0; ks < 16; ks++) {
            int c = ks * 2 + lh;
            #pragma unroll
            for (int pf = 0; pf < 2; pf++) {
                hfrag bf = *(const hfrag*)&Bs[(pf * 32 + l31) * 256 + ((c ^ (l31 & 7)) << 3)];
                acc[pf] = MFMA32(A[ks], bf, acc[pf]);
            }
        }
        float s[2] = {0.f, 0.f};
        #pragma unroll
        for (int q = 0; q < 4; q++) {
            float4 b1v = *(const float4*)&b1p[wv * 32 + q * 8 + 4 * lh];
            float4 w2v = *(const float4*)&w2p[wv * 32 + q * 8 + 4 * lh];
            #pragma unroll
            for (int pf = 0; pf < 2; pf++) {
                float h0 = acc[pf][q * 4 + 0] + b1v.x;
                float h1 = acc[pf][q * 4 + 1] + b1v.y;
                float h2_ = acc[pf][q * 4 + 2] + b1v.z;
                float h3 = acc[pf][q * 4 + 3] + b1v.w;
                s[pf] += w2v.x * (h0 > 0.f ? h0 : 0.f);
                s[pf] += w2v.y * (h1 > 0.f ? h1 : 0.f);
                s[pf] += w2v.z * (h2_ > 0.f ? h2_ : 0.f);
                s[pf] += w2v.w * (h3 > 0.f ? h3 : 0.f);
            }
        }
        s[0] += __shfl_xor(s[0], 32);
        s[1] += __shfl_xor(s[1], 32);
        if (lh == 0) {
            red[wv][l31]      = s[0];
            red[wv][32 + l31] = s[1];
        }
        asm volatile("s_waitcnt lgkmcnt(0)" ::: "memory");
        __builtin_amdgcn_s_barrier();
        if (t < 64) {
            float v = red[0][t] + red[1][t] + red[2][t] + red[3][t] +
                      red[4][t] + red[5][t] + red[6][t] + red[7][t];
            int px = tt * 64 + t;
            if (px < HW) heat[(size_t)(b * PTS + p) * HW + px] = expf(v + b2v);
        }
    };
    compute(tt0, B0);
    asm volatile("s_waitcnt vmcnt(0)" ::: "memory");
    __builtin_amdgcn_s_barrier();
    __builtin_amdgcn_sched_barrier(0);
    compute(tt0 + 1, B1);
}

// ---------------------------------------------------------------------------
// K3: FUSED sampling + merge (32-px tiles).  Phase 3 gather now issues the
// 20 L2 loads per pixel in two explicitly-batched groups of 10 (second batch
// prefetched during the first batch's FMAs) to raise outstanding-load count
// ~5x (was latency-bound at VGPR_Count=40).  Phase 4 A-frags double-buffered.
// ---------------------------------------------------------------------------
__global__ __launch_bounds__(512, 2)
void k_sm(const ushort* __restrict__ efp, const float* __restrict__ heat,
          const float* __restrict__ offs, const ushort* __restrict__ wbm,
          const float* __restrict__ mb, ushort* __restrict__ mgb,
          float* __restrict__ part2)
{
    __shared__ ushort Bs[32 * 512];     // 32 KB sampled tile [px][512]
    __shared__ uint2 s_wo[2][32][20];   // 10 KB weights/offsets
    const int t = threadIdx.x;
    const int wv = t >> 6, ln = t & 63;
    const int l31 = ln & 31, lh = ln >> 5;
    // bijective XCD decode for 475 tiles: q=59, r=3
    const int bid = blockIdx.x;
    const int xcd = bid & 7, ii = bid >> 3;
    const int tile = (xcd < 3 ? xcd * 60 : 180 + (xcd - 3) * 59) + ii;
    const int b = blockIdx.y;
    const int m0 = tile * 32;

    // ---- phase 1: bilinear weights for both p (320 threads) ----
    if (t < 32 * BINS * PTS) {
        int p = t / 160, r = t - p * 160;
        int j = r / BINS, k = r - (r / BINS) * BINS;
        int hw = m0 + j;
        int hh = hw / Ww, ww = hw - hh * Ww;
        const float* heat_bp = heat + (size_t)(b * PTS + p) * HW;
        int chy = (p * BINS + k) * 2;
        float oy = offs[((size_t)b * (PTS * BINS * 2) + chy)     * HW + hw];
        float ox = offs[((size_t)b * (PTS * BINS * 2) + chy + 1) * HW + hw];
        float ysf = (float)hh + oy;
        float xsf = (float)ww + ox;
        float y0 = floorf(ysf), x0 = floorf(xsf);
        #pragma unroll
        for (int dy = 0; dy < 2; dy++)
            #pragma unroll
            for (int dx = 0; dx < 2; dx++) {
                float yi = y0 + dy, xi = x0 + dx;
                float wgt = (1.f - fabsf(ysf - yi)) * (1.f - fabsf(xsf - xi));
                bool valid = (yi >= 0.f) && (yi <= (float)(Hh - 1)) &&
                             (xi >= 0.f) && (xi <= (float)(Ww - 1));
                int yc = (int)yi; yc = yc < 0 ? 0 : (yc > Hh - 1 ? Hh - 1 : yc);
                int xc = (int)xi; xc = xc < 0 ? 0 : (xc > Ww - 1 ? Ww - 1 : xc);
                int idx = yc * Ww + xc;
                float wh = valid ? wgt * heat_bp[idx] : 0.f;
                s_wo[p][j][k * 4 + dy * 2 + dx] =
                    make_uint2(__float_as_uint(wh), (unsigned)idx << 9);
            }
    }
    __syncthreads();
    // ---- phase 2: normalize (64 threads: p = t>>5, px = t&31) ----
    if (t < 64) {
        int p = t >> 5, px = t & 31;
        float s = 0.f;
        #pragma unroll
        for (int u = 0; u < 20; u++) s += __uint_as_float(s_wo[p][px][u].x);
        float inv = 1.f / (s + EPS_DIV);
        #pragma unroll
        for (int u = 0; u < 20; u++) {
            float w = __uint_as_float(s_wo[p][px][u].x) * inv;
            unsigned hw16 = (unsigned)f2h(w);
            s_wo[p][px][u].x = hw16 | (hw16 << 16);
        }
    }
    __syncthreads();

    // ---- phase 3: gather, batched for ILP.  wave wv: p = wv>>2,
    //      pixels (wv&3)*8 .. +7 ----
    {
        const int p = wv >> 2;
        const int jb = (wv & 3) * 8;
        const int g = p * 32 + l31;          // column unit (16B) in [0,64)
        const char* efbase = (const char*)(efp + (size_t)((b * PTS + p) * HW) * Cc)
                             + l31 * 16;
        #pragma unroll 1
        for (int i2 = 0; i2 < 8; i2 += 2) {
            const int j = jb + i2 + lh;
            h2 a0 = (h2){0, 0}, a1 = (h2){0, 0}, a2 = (h2){0, 0}, a3 = (h2){0, 0};
            uint4 vv[10];
            unsigned wu[10];
            #pragma unroll
            for (int u = 0; u < 10; u++) {
                uint2 wo = s_wo[p][j][u];
                wu[u] = wo.x;
                vv[u] = *(const uint4*)(efbase + wo.y);
            }
            #pragma unroll
            for (int u = 0; u < 10; u++) {
                h2 wp = __builtin_bit_cast(h2, wu[u]);
                uint4 v = vv[u];
                uint2 wo2 = s_wo[p][j][u + 10];
                wu[u] = wo2.x;
                vv[u] = *(const uint4*)(efbase + wo2.y);   // prefetch 2nd half
                a0 += wp * __builtin_bit_cast(h2, v.x);
                a1 += wp * __builtin_bit_cast(h2, v.y);
                a2 += wp * __builtin_bit_cast(h2, v.z);
                a3 += wp * __builtin_bit_cast(h2, v.w);
            }
            #pragma unroll
            for (int u = 0; u < 10; u++) {
                h2 wp = __builtin_bit_cast(h2, wu[u]);
                a0 += wp * __builtin_bit_cast(h2, vv[u].x);
                a1 += wp * __builtin_bit_cast(h2, vv[u].y);
                a2 += wp * __builtin_bit_cast(h2, vv[u].z);
                a3 += wp * __builtin_bit_cast(h2, vv[u].w);
            }
            uint4 o = { __builtin_bit_cast(unsigned, a0), __builtin_bit_cast(unsigned, a1),
                        __builtin_bit_cast(unsigned, a2), __builtin_bit_cast(unsigned, a3) };
            *(uint4*)&Bs[j * 512 + ((g ^ j) << 3)] = o;
        }
    }
    __syncthreads();

    // ---- phase 4: merge GEMM (M=256, N=32, K=512); A double-buffered ----
    f32x16 acc;
    #pragma unroll
    for (int r = 0; r < 16; r++) acc[r] = 0.f;
    hfrag Aa[8], Ab[8];
    #pragma unroll
    for (int k8 = 0; k8 < 8; k8++)
        Aa[k8] = *(const hfrag*)&wbm[(((0 * 8 + k8) * 8 + wv) * 64 + ln) * 8];
    #pragma unroll
    for (int k8 = 0; k8 < 8; k8++)
        Ab[k8] = *(const hfrag*)&wbm[(((1 * 8 + k8) * 8 + wv) * 64 + ln) * 8];

    #pragma unroll
    for (int k8 = 0; k8 < 8; k8++) {           // c4 = 0 (Aa), prefetch c4=2
        int c = (0 * 8 + k8) * 2 + lh;
        hfrag bf = *(const hfrag*)&Bs[l31 * 512 + ((c ^ l31) << 3)];
        acc = MFMA32(Aa[k8], bf, acc);
        Aa[k8] = *(const hfrag*)&wbm[(((2 * 8 + k8) * 8 + wv) * 64 + ln) * 8];
    }
    #pragma unroll
    for (int k8 = 0; k8 < 8; k8++) {           // c4 = 1 (Ab), prefetch c4=3
        int c = (1 * 8 + k8) * 2 + lh;
        hfrag bf = *(const hfrag*)&Bs[l31 * 512 + ((c ^ l31) << 3)];
        acc = MFMA32(Ab[k8], bf, acc);
        Ab[k8] = *(const hfrag*)&wbm[(((3 * 8 + k8) * 8 + wv) * 64 + ln) * 8];
    }
    #pragma unroll
    for (int k8 = 0; k8 < 8; k8++) {           // c4 = 2 (Aa)
        int c = (2 * 8 + k8) * 2 + lh;
        hfrag bf = *(const hfrag*)&Bs[l31 * 512 + ((c ^ l31) << 3)];
        acc = MFMA32(Aa[k8], bf, acc);
    }
    #pragma unroll
    for (int k8 = 0; k8 < 8; k8++) {           // c4 = 3 (Ab)
        int c = (3 * 8 + k8) * 2 + lh;
        hfrag bf = *(const hfrag*)&Bs[l31 * 512 + ((c ^ l31) << 3)];
        acc = MFMA32(Ab[k8], bf, acc);
    }

    const int px = m0 + l31;                 // always < HW (475*32 = 15200)
    float sg[4] = {0.f, 0.f, 0.f, 0.f};
    float qg[4] = {0.f, 0.f, 0.f, 0.f};
    #pragma unroll
    for (int q = 0; q < 4; q++) {
        float4 bv = *(const float4*)&mb[wv * 32 + q * 8 + 4 * lh];
        #pragma unroll
        for (int r = 0; r < 4; r++) {
            float bb = r == 0 ? bv.x : (r == 1 ? bv.y : (r == 2 ? bv.z : bv.w));
            float v = acc[q * 4 + r] + bb;
            int ch = wv * 32 + q * 8 + 4 * lh + r;
            mgb[((size_t)b * Cc + ch) * HW + px] = f2h(v);
            sg[q] += v; qg[q] += v * v;
        }
    }
    #pragma unroll
    for (int q = 0; q < 4; q++) {
        #pragma unroll
        for (int off = 1; off <= 32; off <<= 1) {
            sg[q] += __shfl_xor(sg[q], off);
            qg[q] += __shfl_xor(qg[q], off);
        }
    }
    if (ln == 0) {
        #pragma unroll
        for (int q = 0; q < 4; q++) {
            int g = wv * 4 + q;
            size_t idx = ((size_t)(b * 32 + g) * NTILE + tile) * 2;
            part2[idx + 0] = sg[q];
            part2[idx + 1] = qg[q];
        }
    }
}

// ---------------------------------------------------------------------------
// K5: reduce per-tile GN partials -> mean/istd per (b,group)
// ---------------------------------------------------------------------------
__global__ __launch_bounds__(256)
void k_gnfinal(const float* __restrict__ part2, float* __restrict__ statf)
{
    const int bg = blockIdx.x;
    const int t = threadIdx.x;
    float s = 0.f, q = 0.f;
    for (int u = t; u < NTILE; u += 256) {
        s += part2[((size_t)bg * NTILE + u) * 2 + 0];
        q += part2[((size_t)bg * NTILE + u) * 2 + 1];
    }
    #pragma unroll
    for (int off = 1; off <= 32; off <<= 1) {
        s += __shfl_xor(s, off);
        q += __shfl_xor(q, off);
    }
    __shared__ float rs[4], rq[4];
    int wid = t >> 6;
    if ((t & 63) == 0) { rs[wid] = s; rq[wid] = q; }
    __syncthreads();
    if (t == 0) {
        float S = rs[0] + rs[1] + rs[2] + rs[3];
        float Q = rq[0] + rq[1] + rq[2] + rq[3];
        const float n = 8.f * HW;
        float mean = S / n;
        float var  = Q / n - mean * mean;
        statf[bg * 2 + 0] = mean;
        statf[bg * 2 + 1] = rsqrtf(var + GN_EPS);
    }
}

// ---------------------------------------------------------------------------
// K6: apply GN scale/shift + ReLU
// ---------------------------------------------------------------------------
__global__ __launch_bounds__(256)
void k_gnapply(const ushort* __restrict__ mgb, const float* __restrict__ statf,
               const float* __restrict__ gg, const float* __restrict__ gb,
               float* __restrict__ out)
{
    const int i8 = blockIdx.x * 256 + threadIdx.x;
    const int i = i8 * 8;
    const int CHW = Cc * HW;
    const int b = i / CHW;
    const int r = i - b * CHW;
    const int c = r / HW;
    const int g = c >> 3;
    float mean = statf[(b * 32 + g) * 2 + 0];
    float istd = statf[(b * 32 + g) * 2 + 1];
    float sc = istd * gg[c];
    float sh = gb[c] - mean * sc;
    uint4 v = *(const uint4*)(mgb + i);
    float4 o0, o1;
    o0.x = fmaxf(hlo(v.x) * sc + sh, 0.f);
    o0.y = fmaxf(hhi(v.x) * sc + sh, 0.f);
    o0.z = fmaxf(hlo(v.y) * sc + sh, 0.f);
    o0.w = fmaxf(hhi(v.y) * sc + sh, 0.f);
    o1.x = fmaxf(hlo(v.z) * sc + sh, 0.f);
    o1.y = fmaxf(hhi(v.z) * sc + sh, 0.f);
    o1.z = fmaxf(hlo(v.w) * sc + sh, 0.f);
    o1.w = fmaxf(hhi(v.w) * sc + sh, 0.f);
    *(float4*)(out + i)     = o0;
    *(float4*)(out + i + 4) = o1;
}

// ---------------------------------------------------------------------------
extern "C" void kernel_launch(void* const* d_in, const int* in_sizes, int n_in,
                              void* d_out, int out_size, void* d_ws, size_t ws_size,
                              hipStream_t stream)
{
    const float* x    = (const float*)d_in[0];
    const float* offs = (const float*)d_in[1];
    const float* efw  = (const float*)d_in[2];
    const float* efb  = (const float*)d_in[3];
    const float* w1   = (const float*)d_in[4];
    const float* b1   = (const float*)d_in[5];
    const float* w2   = (const float*)d_in[6];
    const float* b2   = (const float*)d_in[7];
    const float* mw   = (const float*)d_in[8];
    const float* mb   = (const float*)d_in[9];
    const float* gg   = (const float*)d_in[10];
    const float* gb   = (const float*)d_in[11];
    float* out = (float*)d_out;

    ushort* wb    = (ushort*)d_ws;
    ushort* wbe   = wb;                          // 131072 (frag order)
    ushort* wb1   = wb + 131072;
    ushort* wbm   = wb + 262144;
    ushort* efp   = wb + 393216;                        // B*P*HW*C fp16
    ushort* xbt   = efp + (size_t)Bx * PTS * HW * Cc;   // B*HW*C fp16
    ushort* mgb   = xbt + (size_t)Bx * HW * Cc;         // B*C*HW fp16
    float*  heat  = (float*)(mgb + (size_t)Bx * Cc * HW);
    float*  part2 = heat + (size_t)Bx * PTS * HW;       // 64*NTILE*2 floats
    float*  statf = part2 + (size_t)64 * NTILE * 2;     // 128 floats

    dim3 blk(256);
    k_pre    <<<dim3(7792),             blk, 0, stream>>>(efw, w1, mw, wb, x, xbt);
    k_ef     <<<dim3(119, Bx),    dim3(512), 0, stream>>>(xbt, wbe, efb, efp);
    k_heat   <<<dim3(119, 4),     dim3(512), 0, stream>>>(efp, wb1, b1, w2, b2, heat);
    k_sm     <<<dim3(475, Bx),    dim3(512), 0, stream>>>(efp, heat, offs, wbm, mb, mgb, part2);
    k_gnfinal<<<dim3(64),               blk, 0, stream>>>(part2, statf);
    k_gnapply<<<dim3(Bx * Cc * HW / 8 / 256), blk, 0, stream>>>(mgb, statf, gg, gb, out);
}

// Round 7
// 195.428 us; speedup vs baseline: 1.0711x; 1.0086x over previous
//
#include <hip/hip_runtime.h>

#define BINS 5
#define PTS  2
constexpr int Bx = 2, Cc = 256, Hh = 100, Ww = 152;
constexpr int HW = Hh * Ww;          // 15200
constexpr int NTILE = 475;           // 32-px tiles (exact)
constexpr float EPS_DIV = 1e-6f;
constexpr float GN_EPS  = 1e-5f;

typedef __attribute__((ext_vector_type(8)))  _Float16 hfrag;  // 8 fp16
typedef __attribute__((ext_vector_type(2)))  _Float16 h2;
typedef __attribute__((ext_vector_type(16))) float    f32x16; // 32x32 MFMA C/D

__device__ __forceinline__ ushort f2h(float f) {
    return __builtin_bit_cast(ushort, (_Float16)f);
}
__device__ __forceinline__ float hlo(unsigned u) {
    return (float)__builtin_bit_cast(_Float16, (ushort)(u & 0xffffu));
}
__device__ __forceinline__ float hhi(unsigned u) {
    return (float)__builtin_bit_cast(_Float16, (ushort)(u >> 16));
}

#define GLL16(g, l) __builtin_amdgcn_global_load_lds( \
    (const __attribute__((address_space(1))) unsigned*)(g), \
    (__attribute__((address_space(3))) unsigned*)(l), 16, 0, 0)

#define MFMA32(a, b, c) __builtin_amdgcn_mfma_f32_32x32x16_f16(a, b, c, 0, 0, 0)

// ---------------------------------------------------------------------------
// K0: fused preprocessing.  Blocks 0..191: weight convert to fp16 in
// 32x32x16-MFMA fragment order.  Blocks 192..7791: x transpose+convert.
// ---------------------------------------------------------------------------
__global__ __launch_bounds__(256)
void k_pre(const float* __restrict__ efw, const float* __restrict__ w1,
           const float* __restrict__ mw, ushort* __restrict__ wb,
           const float* __restrict__ x, ushort* __restrict__ xbt)
{
    __shared__ float tile[32][33];
    const int bid = blockIdx.x;
    const int t = threadIdx.x;
    if (bid < 192) {
        int gid = bid * 256 + t;
        int i = gid * 8;
        int arr = i >> 17, off = i & 131071;
        const float* src = arr == 0 ? efw : (arr == 1 ? w1 : mw);
        float4 v0 = *(const float4*)(src + off);
        float4 v1 = *(const float4*)(src + off + 4);
        int outaddr;
        if (arr == 0) {                // ef_w: M=512, K=256
            int m = off >> 8, k = off & 255;
            outaddr = (((k >> 4) * 16 + (m >> 5)) * 64 + (m & 31) + 32 * ((k >> 3) & 1)) * 8;
        } else if (arr == 1) {         // hm1_w: per p, M=256, K=256
            int p = off >> 16, r = off & 65535;
            int m = r >> 8, k = r & 255;
            outaddr = p * 65536 +
                      (((k >> 4) * 8 + (m >> 5)) * 64 + (m & 31) + 32 * ((k >> 3) & 1)) * 8;
        } else {                       // merge_w: M=256, K=512
            int m = off >> 9, k = off & 511;
            outaddr = (((k >> 4) * 8 + (m >> 5)) * 64 + (m & 31) + 32 * ((k >> 3) & 1)) * 8;
        }
        ushort o[8] = { f2h(v0.x), f2h(v0.y), f2h(v0.z), f2h(v0.w),
                        f2h(v1.x), f2h(v1.y), f2h(v1.z), f2h(v1.w) };
        *(uint4*)(wb + arr * 131072 + outaddr) = *(uint4*)o;
    } else {
        int r = bid - 192;             // 0..7599
        const int b = r / 3800; r -= b * 3800;
        const int c0 = (r / 475) * 32;
        const int hw0 = (r % 475) * 32;
        const float* xb = x + ((size_t)b * Cc + c0) * HW + hw0;
        const int tx = t & 31, ty = t >> 5;
        #pragma unroll
        for (int rr = 0; rr < 4; rr++) {
            int c = ty + rr * 8;
            tile[c][tx] = xb[(size_t)c * HW + tx];
        }
        __syncthreads();
        const int hwl = t >> 3, c4 = (t & 7) * 4;
        ushort4 o = { f2h(tile[c4 + 0][hwl]), f2h(tile[c4 + 1][hwl]),
                      f2h(tile[c4 + 2][hwl]), f2h(tile[c4 + 3][hwl]) };
        *(ushort4*)&xbt[((size_t)b * HW + hw0 + hwl) * Cc + c0 + c4] = o;
    }
}

// ---------------------------------------------------------------------------
// K1: efp = ef_w @ x + ef_b.  A (512x256) in registers, LDS = B only
// (2 x 32KB dbuf), 32x32x16 MFMA, counted vmcnt.  (proven R3)
// ---------------------------------------------------------------------------
__global__ __launch_bounds__(512, 2)
void k_ef(const ushort* __restrict__ xbt, const ushort* __restrict__ wbe,
          const float* __restrict__ efb, ushort* __restrict__ efp)
{
    __shared__ ushort B0[64 * 256];
    __shared__ ushort B1[64 * 256];
    const int t = threadIdx.x;
    const int wv = t >> 6, ln = t & 63;
    const int l31 = ln & 31, lh = ln >> 5;
    const int b = blockIdx.y;
    const int tt0 = blockIdx.x * 2;
    const ushort* xb = xbt + (size_t)b * HW * Cc;

    hfrag A[2][16];
    #pragma unroll
    for (int mf = 0; mf < 2; mf++)
        #pragma unroll
        for (int ks = 0; ks < 16; ks++)
            A[mf][ks] = *(const hfrag*)&wbe[((ks * 16 + (wv * 2 + mf)) * 64 + ln) * 8];
    __builtin_amdgcn_sched_barrier(0);

    auto stageB = [&](int tt, ushort* dst) {
        int tp0 = tt * 64;
        #pragma unroll
        for (int j = 0; j < 4; j++) {
            int unit = j * 512 + t;
            int prow = unit >> 5, c8 = unit & 31;
            int pq = tp0 + prow; if (pq > HW - 1) pq = HW - 1;
            const ushort* g = xb + (size_t)pq * Cc + ((c8 ^ (prow & 7)) << 3);
            ushort* l = dst + (j * 512 + wv * 64) * 8;
            GLL16(g, l);
        }
    };
    stageB(tt0, B0);
    stageB(tt0 + 1, B1);
    __builtin_amdgcn_sched_barrier(0);
    asm volatile("s_waitcnt vmcnt(4)" ::: "memory");
    __builtin_amdgcn_s_barrier();
    __builtin_amdgcn_sched_barrier(0);

    auto compute = [&](int tt, const ushort* Bs) {
        f32x16 acc[2][2];
        #pragma unroll
        for (int mf = 0; mf < 2; mf++)
            #pragma unroll
            for (int pf = 0; pf < 2; pf++)
                #pragma unroll
                for (int r = 0; r < 16; r++) acc[mf][pf][r] = 0.f;
        #pragma unroll
        for (int ks = 0; ks < 16; ks++) {
            int c = ks * 2 + lh;
            #pragma unroll
            for (int pf = 0; pf < 2; pf++) {
                hfrag bf = *(const hfrag*)&Bs[(pf * 32 + l31) * 256 + ((c ^ (l31 & 7)) << 3)];
                acc[0][pf] = MFMA32(A[0][ks], bf, acc[0][pf]);
                acc[1][pf] = MFMA32(A[1][ks], bf, acc[1][pf]);
            }
        }
        const int tp0 = tt * 64;
        #pragma unroll
        for (int mf = 0; mf < 2; mf++) {
            int m0 = wv * 2 + mf;
            const int p_ = m0 >> 3;
            ushort* outb = efp + (size_t)((b * PTS + p_) * HW) * Cc;
            int chb = (m0 * 32) & 255;
            #pragma unroll
            for (int q = 0; q < 4; q++) {
                float4 bv = *(const float4*)&efb[m0 * 32 + q * 8 + 4 * lh];
                #pragma unroll
                for (int pf = 0; pf < 2; pf++) {
                    int px = tp0 + pf * 32 + l31;
                    if (px < HW) {
                        int ch = chb + q * 8 + 4 * lh;
                        ushort4 o = { f2h(acc[mf][pf][q * 4 + 0] + bv.x),
                                      f2h(acc[mf][pf][q * 4 + 1] + bv.y),
                                      f2h(acc[mf][pf][q * 4 + 2] + bv.z),
                                      f2h(acc[mf][pf][q * 4 + 3] + bv.w) };
                        *(ushort4*)&outb[(size_t)px * Cc + ch] = o;
                    }
                }
            }
        }
    };
    compute(tt0, B0);
    asm volatile("s_waitcnt vmcnt(0)" ::: "memory");
    __builtin_amdgcn_s_barrier();
    __builtin_amdgcn_sched_barrier(0);
    compute(tt0 + 1, B1);
}

// ---------------------------------------------------------------------------
// K2: heat = exp(w2.relu(w1@efp + b1) + b2) fused (proven R3)
// ---------------------------------------------------------------------------
__global__ __launch_bounds__(512, 2)
void k_heat(const ushort* __restrict__ efp, const ushort* __restrict__ wb1,
            const float* __restrict__ b1, const float* __restrict__ w2,
            const float* __restrict__ b2, float* __restrict__ heat)
{
    __shared__ ushort B0[64 * 256];
    __shared__ ushort B1[64 * 256];
    __shared__ float red[8][64];
    const int t = threadIdx.x;
    const int wv = t >> 6, ln = t & 63;
    const int l31 = ln & 31, lh = ln >> 5;
    const int zz = blockIdx.y;
    const int b = zz >> 1, p = zz & 1;
    const int tt0 = blockIdx.x * 2;
    const ushort* eb = efp + (size_t)((b * PTS + p) * HW) * Cc;
    const float* b1p = b1 + p * 256;
    const float* w2p = w2 + p * 256;
    const float b2v = b2[p];

    hfrag A[16];
    #pragma unroll
    for (int ks = 0; ks < 16; ks++)
        A[ks] = *(const hfrag*)&wb1[p * 65536 + ((ks * 8 + wv) * 64 + ln) * 8];
    __builtin_amdgcn_sched_barrier(0);

    auto stageB = [&](int tt, ushort* dst) {
        int tp0 = tt * 64;
        #pragma unroll
        for (int j = 0; j < 4; j++) {
            int unit = j * 512 + t;
            int prow = unit >> 5, c8 = unit & 31;
            int pq = tp0 + prow; if (pq > HW - 1) pq = HW - 1;
            const ushort* g = eb + (size_t)pq * Cc + ((c8 ^ (prow & 7)) << 3);
            ushort* l = dst + (j * 512 + wv * 64) * 8;
            GLL16(g, l);
        }
    };
    stageB(tt0, B0);
    stageB(tt0 + 1, B1);
    __builtin_amdgcn_sched_barrier(0);
    asm volatile("s_waitcnt vmcnt(4)" ::: "memory");
    __builtin_amdgcn_s_barrier();
    __builtin_amdgcn_sched_barrier(0);

    auto compute = [&](int tt, const ushort* Bs) {
        f32x16 acc[2];
        #pragma unroll
        for (int pf = 0; pf < 2; pf++)
            #pragma unroll
            for (int r = 0; r < 16; r++) acc[pf][r] = 0.f;
        #pragma unroll
        for (int ks = 0; ks < 16; ks++) {
            int c = ks * 2 + lh;
            #pragma unroll
            for (int pf = 0; pf < 2; pf++) {
                hfrag bf = *(const hfrag*)&Bs[(pf * 32 + l31) * 256 + ((c ^ (l31 & 7)) << 3)];
                acc[pf] = MFMA32(A[ks], bf, acc[pf]);
            }
        }
        float s[2] = {0.f, 0.f};
        #pragma unroll
        for (int q = 0; q < 4; q++) {
            float4 b1v = *(const float4*)&b1p[wv * 32 + q * 8 + 4 * lh];
            float4 w2v = *(const float4*)&w2p[wv * 32 + q * 8 + 4 * lh];
            #pragma unroll
            for (int pf = 0; pf < 2; pf++) {
                float h0 = acc[pf][q * 4 + 0] + b1v.x;
                float h1 = acc[pf][q * 4 + 1] + b1v.y;
                float h2_ = acc[pf][q * 4 + 2] + b1v.z;
                float h3 = acc[pf][q * 4 + 3] + b1v.w;
                s[pf] += w2v.x * (h0 > 0.f ? h0 : 0.f);
                s[pf] += w2v.y * (h1 > 0.f ? h1 : 0.f);
                s[pf] += w2v.z * (h2_ > 0.f ? h2_ : 0.f);
                s[pf] += w2v.w * (h3 > 0.f ? h3 : 0.f);
            }
        }
        s[0] += __shfl_xor(s[0], 32);
        s[1] += __shfl_xor(s[1], 32);
        if (lh == 0) {
            red[wv][l31]      = s[0];
            red[wv][32 + l31] = s[1];
        }
        asm volatile("s_waitcnt lgkmcnt(0)" ::: "memory");
        __builtin_amdgcn_s_barrier();
        if (t < 64) {
            float v = red[0][t] + red[1][t] + red[2][t] + red[3][t] +
                      red[4][t] + red[5][t] + red[6][t] + red[7][t];
            int px = tt * 64 + t;
            if (px < HW) heat[(size_t)(b * PTS + p) * HW + px] = expf(v + b2v);
        }
    };
    compute(tt0, B0);
    asm volatile("s_waitcnt vmcnt(0)" ::: "memory");
    __builtin_amdgcn_s_barrier();
    __builtin_amdgcn_sched_barrier(0);
    compute(tt0 + 1, B1);
}

// ---------------------------------------------------------------------------
// K3: FUSED sampling + merge (32-px tiles).  LDS cut to 40448 B (split
// weight/offset arrays) -> 4 blocks/CU = 32 waves (HW max) AND the full
// 950-block grid is co-resident (no dispatch tail).  VGPR pinned <=64 via
// launch_bounds(512,8) so occupancy is LDS-limited only.
// ---------------------------------------------------------------------------
__global__ __launch_bounds__(512, 8)
void k_sm(const ushort* __restrict__ efp, const float* __restrict__ heat,
          const float* __restrict__ offs, const ushort* __restrict__ wbm,
          const float* __restrict__ mb, ushort* __restrict__ mgb,
          float* __restrict__ part2)
{
    __shared__ ushort Bs[32 * 512];       // 32768 B sampled tile [px][512]
    __shared__ unsigned s_w[2][32][20];   // 5120 B: f32 weight -> fp16 pair
    __shared__ ushort   s_o[2][32][20];   // 2560 B: sample row index
    const int t = threadIdx.x;
    const int wv = t >> 6, ln = t & 63;
    const int l31 = ln & 31, lh = ln >> 5;
    // bijective XCD decode for 475 tiles: q=59, r=3
    const int bid = blockIdx.x;
    const int xcd = bid & 7, ii = bid >> 3;
    const int tile = (xcd < 3 ? xcd * 60 : 180 + (xcd - 3) * 59) + ii;
    const int b = blockIdx.y;
    const int m0 = tile * 32;

    // ---- phase 1: bilinear weights for both p (320 threads) ----
    if (t < 32 * BINS * PTS) {
        int p = t / 160, r = t - p * 160;
        int j = r / BINS, k = r - (r / BINS) * BINS;
        int hw = m0 + j;
        int hh = hw / Ww, ww = hw - hh * Ww;
        const float* heat_bp = heat + (size_t)(b * PTS + p) * HW;
        int chy = (p * BINS + k) * 2;
        float oy = offs[((size_t)b * (PTS * BINS * 2) + chy)     * HW + hw];
        float ox = offs[((size_t)b * (PTS * BINS * 2) + chy + 1) * HW + hw];
        float ysf = (float)hh + oy;
        float xsf = (float)ww + ox;
        float y0 = floorf(ysf), x0 = floorf(xsf);
        #pragma unroll
        for (int dy = 0; dy < 2; dy++)
            #pragma unroll
            for (int dx = 0; dx < 2; dx++) {
                float yi = y0 + dy, xi = x0 + dx;
                float wgt = (1.f - fabsf(ysf - yi)) * (1.f - fabsf(xsf - xi));
                bool valid = (yi >= 0.f) && (yi <= (float)(Hh - 1)) &&
                             (xi >= 0.f) && (xi <= (float)(Ww - 1));
                int yc = (int)yi; yc = yc < 0 ? 0 : (yc > Hh - 1 ? Hh - 1 : yc);
                int xc = (int)xi; xc = xc < 0 ? 0 : (xc > Ww - 1 ? Ww - 1 : xc);
                int idx = yc * Ww + xc;
                float wh = valid ? wgt * heat_bp[idx] : 0.f;
                int slot = k * 4 + dy * 2 + dx;
                s_w[p][j][slot] = __float_as_uint(wh);
                s_o[p][j][slot] = (ushort)idx;
            }
    }
    __syncthreads();
    // ---- phase 2: normalize + pack fp16 pair (64 threads) ----
    if (t < 64) {
        int p = t >> 5, px = t & 31;
        float s = 0.f;
        #pragma unroll
        for (int u = 0; u < 20; u++) s += __uint_as_float(s_w[p][px][u]);
        float inv = 1.f / (s + EPS_DIV);
        #pragma unroll
        for (int u = 0; u < 20; u++) {
            float w = __uint_as_float(s_w[p][px][u]) * inv;
            unsigned hw16 = (unsigned)f2h(w);
            s_w[p][px][u] = hw16 | (hw16 << 16);
        }
    }
    __syncthreads();

    // ---- phase 3: gather.  wave wv: p = wv>>2, pixels (wv&3)*8 .. +7 ----
    {
        const int p = wv >> 2;
        const int jb = (wv & 3) * 8;
        const int g = p * 32 + l31;          // column unit (16B) in [0,64)
        const char* efbase = (const char*)(efp + (size_t)((b * PTS + p) * HW) * Cc)
                             + l31 * 16;
        #pragma unroll
        for (int i2 = 0; i2 < 8; i2 += 2) {
            const int j = jb + i2 + lh;
            h2 a0 = (h2){0, 0}, a1 = (h2){0, 0}, a2 = (h2){0, 0}, a3 = (h2){0, 0};
            #pragma unroll
            for (int u = 0; u < 20; u++) {
                unsigned wu = s_w[p][j][u];
                unsigned idx = s_o[p][j][u];
                uint4 v = *(const uint4*)(efbase + ((size_t)idx << 9));
                h2 wp = __builtin_bit_cast(h2, wu);
                a0 += wp * __builtin_bit_cast(h2, v.x);
                a1 += wp * __builtin_bit_cast(h2, v.y);
                a2 += wp * __builtin_bit_cast(h2, v.z);
                a3 += wp * __builtin_bit_cast(h2, v.w);
            }
            uint4 o = { __builtin_bit_cast(unsigned, a0), __builtin_bit_cast(unsigned, a1),
                        __builtin_bit_cast(unsigned, a2), __builtin_bit_cast(unsigned, a3) };
            *(uint4*)&Bs[j * 512 + ((g ^ j) << 3)] = o;
        }
    }
    __syncthreads();

    // ---- phase 4: merge GEMM (M=256, N=32, K=512); A streamed from L2 ----
    f32x16 acc;
    #pragma unroll
    for (int r = 0; r < 16; r++) acc[r] = 0.f;
    #pragma unroll 1
    for (int c4 = 0; c4 < 4; c4++) {
        hfrag A8[8];
        #pragma unroll
        for (int k8 = 0; k8 < 8; k8++)
            A8[k8] = *(const hfrag*)&wbm[(((c4 * 8 + k8) * 8 + wv) * 64 + ln) * 8];
        #pragma unroll
        for (int k8 = 0; k8 < 8; k8++) {
            int c = (c4 * 8 + k8) * 2 + lh;
            hfrag bf = *(const hfrag*)&Bs[l31 * 512 + ((c ^ l31) << 3)];
            acc = MFMA32(A8[k8], bf, acc);
        }
    }

    const int px = m0 + l31;                 // always < HW (475*32 = 15200)
    float sg[4] = {0.f, 0.f, 0.f, 0.f};
    float qg[4] = {0.f, 0.f, 0.f, 0.f};
    #pragma unroll
    for (int q = 0; q < 4; q++) {
        float4 bv = *(const float4*)&mb[wv * 32 + q * 8 + 4 * lh];
        #pragma unroll
        for (int r = 0; r < 4; r++) {
            float bb = r == 0 ? bv.x : (r == 1 ? bv.y : (r == 2 ? bv.z : bv.w));
            float v = acc[q * 4 + r] + bb;
            int ch = wv * 32 + q * 8 + 4 * lh + r;
            mgb[((size_t)b * Cc + ch) * HW + px] = f2h(v);
            sg[q] += v; qg[q] += v * v;
        }
    }
    #pragma unroll
    for (int q = 0; q < 4; q++) {
        #pragma unroll
        for (int off = 1; off <= 32; off <<= 1) {
            sg[q] += __shfl_xor(sg[q], off);
            qg[q] += __shfl_xor(qg[q], off);
        }
    }
    if (ln == 0) {
        #pragma unroll
        for (int q = 0; q < 4; q++) {
            int g = wv * 4 + q;
            size_t idx = ((size_t)(b * 32 + g) * NTILE + tile) * 2;
            part2[idx + 0] = sg[q];
            part2[idx + 1] = qg[q];
        }
    }
}

// ---------------------------------------------------------------------------
// K5: reduce per-tile GN partials -> mean/istd per (b,group)
// ---------------------------------------------------------------------------
__global__ __launch_bounds__(256)
void k_gnfinal(const float* __restrict__ part2, float* __restrict__ statf)
{
    const int bg = blockIdx.x;
    const int t = threadIdx.x;
    float s = 0.f, q = 0.f;
    for (int u = t; u < NTILE; u += 256) {
        s += part2[((size_t)bg * NTILE + u) * 2 + 0];
        q += part2[((size_t)bg * NTILE + u) * 2 + 1];
    }
    #pragma unroll
    for (int off = 1; off <= 32; off <<= 1) {
        s += __shfl_xor(s, off);
        q += __shfl_xor(q, off);
    }
    __shared__ float rs[4], rq[4];
    int wid = t >> 6;
    if ((t & 63) == 0) { rs[wid] = s; rq[wid] = q; }
    __syncthreads();
    if (t == 0) {
        float S = rs[0] + rs[1] + rs[2] + rs[3];
        float Q = rq[0] + rq[1] + rq[2] + rq[3];
        const float n = 8.f * HW;
        float mean = S / n;
        float var  = Q / n - mean * mean;
        statf[bg * 2 + 0] = mean;
        statf[bg * 2 + 1] = rsqrtf(var + GN_EPS);
    }
}

// ---------------------------------------------------------------------------
// K6: apply GN scale/shift + ReLU
// ---------------------------------------------------------------------------
__global__ __launch_bounds__(256)
void k_gnapply(const ushort* __restrict__ mgb, const float* __restrict__ statf,
               const float* __restrict__ gg, const float* __restrict__ gb,
               float* __restrict__ out)
{
    const int i8 = blockIdx.x * 256 + threadIdx.x;
    const int i = i8 * 8;
    const int CHW = Cc * HW;
    const int b = i / CHW;
    const int r = i - b * CHW;
    const int c = r / HW;
    const int g = c >> 3;
    float mean = statf[(b * 32 + g) * 2 + 0];
    float istd = statf[(b * 32 + g) * 2 + 1];
    float sc = istd * gg[c];
    float sh = gb[c] - mean * sc;
    uint4 v = *(const uint4*)(mgb + i);
    float4 o0, o1;
    o0.x = fmaxf(hlo(v.x) * sc + sh, 0.f);
    o0.y = fmaxf(hhi(v.x) * sc + sh, 0.f);
    o0.z = fmaxf(hlo(v.y) * sc + sh, 0.f);
    o0.w = fmaxf(hhi(v.y) * sc + sh, 0.f);
    o1.x = fmaxf(hlo(v.z) * sc + sh, 0.f);
    o1.y = fmaxf(hhi(v.z) * sc + sh, 0.f);
    o1.z = fmaxf(hlo(v.w) * sc + sh, 0.f);
    o1.w = fmaxf(hhi(v.w) * sc + sh, 0.f);
    *(float4*)(out + i)     = o0;
    *(float4*)(out + i + 4) = o1;
}

// ---------------------------------------------------------------------------
extern "C" void kernel_launch(void* const* d_in, const int* in_sizes, int n_in,
                              void* d_out, int out_size, void* d_ws, size_t ws_size,
                              hipStream_t stream)
{
    const float* x    = (const float*)d_in[0];
    const float* offs = (const float*)d_in[1];
    const float* efw  = (const float*)d_in[2];
    const float* efb  = (const float*)d_in[3];
    const float* w1   = (const float*)d_in[4];
    const float* b1   = (const float*)d_in[5];
    const float* w2   = (const float*)d_in[6];
    const float* b2   = (const float*)d_in[7];
    const float* mw   = (const float*)d_in[8];
    const float* mb   = (const float*)d_in[9];
    const float* gg   = (const float*)d_in[10];
    const float* gb   = (const float*)d_in[11];
    float* out = (float*)d_out;

    ushort* wb    = (ushort*)d_ws;
    ushort* wbe   = wb;                          // 131072 (frag order)
    ushort* wb1   = wb + 131072;
    ushort* wbm   = wb + 262144;
    ushort* efp   = wb + 393216;                        // B*P*HW*C fp16
    ushort* xbt   = efp + (size_t)Bx * PTS * HW * Cc;   // B*HW*C fp16
    ushort* mgb   = xbt + (size_t)Bx * HW * Cc;         // B*C*HW fp16
    float*  heat  = (float*)(mgb + (size_t)Bx * Cc * HW);
    float*  part2 = heat + (size_t)Bx * PTS * HW;       // 64*NTILE*2 floats
    float*  statf = part2 + (size_t)64 * NTILE * 2;     // 128 floats

    dim3 blk(256);
    k_pre    <<<dim3(7792),             blk, 0, stream>>>(efw, w1, mw, wb, x, xbt);
    k_ef     <<<dim3(119, Bx),    dim3(512), 0, stream>>>(xbt, wbe, efb, efp);
    k_heat   <<<dim3(119, 4),     dim3(512), 0, stream>>>(efp, wb1, b1, w2, b2, heat);
    k_sm     <<<dim3(475, Bx),    dim3(512), 0, stream>>>(efp, heat, offs, wbm, mb, mgb, part2);
    k_gnfinal<<<dim3(64),               blk, 0, stream>>>(part2, statf);
    k_gnapply<<<dim3(Bx * Cc * HW / 8 / 256), blk, 0, stream>>>(mgb, statf, gg, gb, out);
}